// Round 1
// baseline (7178.171 us; speedup 1.0000x reference)
//
#include <hip/hip_runtime.h>
#include <math.h>

#define Vv 32000
#define Dm 216
#define NLAY 11
#define NHh 4
#define HDd 54
#define FFf 864
#define Bb 2
#define Ss 1024
#define Tt (Bb*Ss)
#define EPSf 1e-5f
#define QKVW 648   // 3*Dm

// ---------------- embed gather ----------------
__global__ void k_embed(const int* __restrict__ ids, const float* __restrict__ emb,
                        float* __restrict__ x) {
    int t = blockIdx.x;
    int id = ids[t];
    for (int d = threadIdx.x; d < Dm; d += blockDim.x)
        x[(size_t)t * Dm + d] = emb[(size_t)id * Dm + d];
}

// ---------------- rope tables ----------------
__global__ void k_rope_tables(float* __restrict__ cosb, float* __restrict__ sinb) {
    int s = blockIdx.x;
    for (int d = threadIdx.x; d < HDd; d += blockDim.x) {
        int j = d % (HDd / 2);
        float inv = powf(10000.0f, -2.0f * (float)j / (float)HDd);
        float f = (float)s * inv;
        cosb[s * HDd + d] = cosf(f);
        sinb[s * HDd + d] = sinf(f);
    }
}

// ---------------- rmsnorm: one wave per token ----------------
__global__ void k_rmsnorm(const float* __restrict__ x, const float* __restrict__ w,
                          float* __restrict__ h) {
    int t = blockIdx.x;
    const float* xr = x + (size_t)t * Dm;
    float ss = 0.f;
    for (int d = threadIdx.x; d < Dm; d += 64) { float v = xr[d]; ss += v * v; }
    for (int o = 32; o; o >>= 1) ss += __shfl_down(ss, o, 64);
    float r = __shfl(ss, 0, 64);
    r = rsqrtf(r / (float)Dm + EPSf);
    for (int d = threadIdx.x; d < Dm; d += 64)
        h[(size_t)t * Dm + d] = xr[d] * r * w[d];
}

// ---------------- generic tiled GEMM: out[m,n] = (res?) + sum_k A[m,k]*W[n,k] ----------------
#define TS 16
__global__ void k_gemm(const float* __restrict__ A, const float* __restrict__ W,
                       const float* __restrict__ res, float* __restrict__ out,
                       int M, int N, int K) {
    __shared__ float As[TS][TS + 1];
    __shared__ float Wsm[TS][TS + 1];
    const int tx = threadIdx.x, ty = threadIdx.y;
    const int m = blockIdx.y * TS + ty;
    const int n = blockIdx.x * TS + tx;
    float acc = 0.f;
    for (int k0 = 0; k0 < K; k0 += TS) {
        int ka = k0 + tx;
        As[ty][tx] = (m < M && ka < K) ? A[(size_t)m * K + ka] : 0.f;
        int nw = blockIdx.x * TS + ty;
        Wsm[ty][tx] = (nw < N && ka < K) ? W[(size_t)nw * K + ka] : 0.f;
        __syncthreads();
        #pragma unroll
        for (int kk = 0; kk < TS; ++kk) acc += As[ty][kk] * Wsm[tx][kk];
        __syncthreads();
    }
    if (m < M && n < N) {
        float r = res ? res[(size_t)m * N + n] : 0.f;
        out[(size_t)m * N + n] = r + acc;
    }
}

// ---------------- fused gate/up GEMM + SiLU ----------------
__global__ void k_gateup(const float* __restrict__ A, const float* __restrict__ Wg,
                         const float* __restrict__ Wu, float* __restrict__ act,
                         int M, int N, int K) {
    __shared__ float As[TS][TS + 1];
    __shared__ float Gs[TS][TS + 1];
    __shared__ float Us[TS][TS + 1];
    const int tx = threadIdx.x, ty = threadIdx.y;
    const int m = blockIdx.y * TS + ty;
    const int n = blockIdx.x * TS + tx;
    float ag = 0.f, au = 0.f;
    for (int k0 = 0; k0 < K; k0 += TS) {
        int ka = k0 + tx;
        As[ty][tx] = (m < M && ka < K) ? A[(size_t)m * K + ka] : 0.f;
        int nw = blockIdx.x * TS + ty;
        Gs[ty][tx] = (nw < N && ka < K) ? Wg[(size_t)nw * K + ka] : 0.f;
        Us[ty][tx] = (nw < N && ka < K) ? Wu[(size_t)nw * K + ka] : 0.f;
        __syncthreads();
        #pragma unroll
        for (int kk = 0; kk < TS; ++kk) {
            ag += As[ty][kk] * Gs[tx][kk];
            au += As[ty][kk] * Us[tx][kk];
        }
        __syncthreads();
    }
    if (m < M && n < N) {
        float sg = ag / (1.f + expf(-ag));
        act[(size_t)m * N + n] = sg * au;
    }
}

// ---------------- in-place RoPE on q,k halves of qkv ----------------
__global__ void k_rope(float* __restrict__ qkv, const float* __restrict__ cosb,
                       const float* __restrict__ sinb) {
    const int t = blockIdx.x;
    const int s = t % Ss;
    float* base = qkv + (size_t)t * QKVW;
    const int HALF = HDd / 2; // 27
    int i = threadIdx.x;
    if (i < 2 * NHh * HALF) {
        int which = i / (NHh * HALF);      // 0=q, 1=k
        int rem = i % (NHh * HALF);
        int hh = rem / HALF;
        int d = rem % HALF;
        float* ptr = base + which * Dm + hh * HDd;
        float x1 = ptr[d], x2 = ptr[d + HALF];
        float c1 = cosb[s * HDd + d], s1 = sinb[s * HDd + d];
        float c2 = cosb[s * HDd + d + HALF], s2 = sinb[s * HDd + d + HALF];
        ptr[d]        = x1 * c1 - x2 * s1;
        ptr[d + HALF] = x2 * c2 + x1 * s2;
    }
}

// ---------------- attention: one block per (b,h,q) row ----------------
__global__ void k_attn(const float* __restrict__ qkv, float* __restrict__ aout) {
    const int q = blockIdx.x, h = blockIdx.y, b = blockIdx.z;
    const int tid = threadIdx.x;
    __shared__ float p[Ss];
    __shared__ float qv[HDd];
    __shared__ float rmax[4], rsum[4];
    const size_t base = (size_t)b * Ss * QKVW;
    const float* qrow = qkv + base + (size_t)q * QKVW + h * HDd;
    if (tid < HDd) qv[tid] = qrow[tid];
    __syncthreads();
    const int nk = q + 1;
    const float scale = 0.13608276348795434f; // 54^-0.5
    float lmax = -3.0e38f;
    for (int k = tid; k < nk; k += 256) {
        const float* krow = qkv + base + (size_t)k * QKVW + Dm + h * HDd;
        float acc = 0.f;
        #pragma unroll
        for (int d = 0; d < HDd; ++d) acc += qv[d] * krow[d];
        acc *= scale;
        p[k] = acc;
        lmax = fmaxf(lmax, acc);
    }
    for (int o = 32; o; o >>= 1) lmax = fmaxf(lmax, __shfl_down(lmax, o, 64));
    if ((tid & 63) == 0) rmax[tid >> 6] = lmax;
    __syncthreads();
    const float m = fmaxf(fmaxf(rmax[0], rmax[1]), fmaxf(rmax[2], rmax[3]));
    float lsum = 0.f;
    for (int k = tid; k < nk; k += 256) {
        float e = expf(p[k] - m);
        p[k] = e;
        lsum += e;
    }
    for (int o = 32; o; o >>= 1) lsum += __shfl_down(lsum, o, 64);
    if ((tid & 63) == 0) rsum[tid >> 6] = lsum;
    __syncthreads();
    const float inv = 1.f / (rsum[0] + rsum[1] + rsum[2] + rsum[3]);
    for (int d = tid; d < HDd; d += 256) {
        const float* vcol = qkv + base + 2 * Dm + h * HDd + d;
        float acc = 0.f;
        for (int k = 0; k < nk; ++k) acc += p[k] * vcol[(size_t)k * QKVW];
        aout[(size_t)(b * Ss + q) * Dm + h * HDd + d] = acc * inv;
    }
}

extern "C" void kernel_launch(void* const* d_in, const int* in_sizes, int n_in,
                              void* d_out, int out_size, void* d_ws, size_t ws_size,
                              hipStream_t stream) {
    const int*   ids    = (const int*)d_in[0];
    const float* emb    = (const float*)d_in[1];
    const float* ln1_w  = (const float*)d_in[2];
    const float* qkv_w  = (const float*)d_in[3];
    const float* o_w    = (const float*)d_in[4];
    const float* ln2_w  = (const float*)d_in[5];
    const float* gate_w = (const float*)d_in[6];
    const float* up_w   = (const float*)d_in[7];
    const float* down_w = (const float*)d_in[8];
    const float* norm_w = (const float*)d_in[9];
    const float* lm_w   = (const float*)d_in[10];
    float* out = (float*)d_out;

    float* ws = (float*)d_ws;
    size_t off = 0;
    float* x    = ws + off; off += (size_t)Tt * Dm;
    float* h    = ws + off; off += (size_t)Tt * Dm;
    float* qkv  = ws + off; off += (size_t)Tt * QKVW;
    float* aout = ws + off; off += (size_t)Tt * Dm;
    float* act  = ws + off; off += (size_t)Tt * FFf;
    float* cosb = ws + off; off += (size_t)Ss * HDd;
    float* sinb = ws + off; off += (size_t)Ss * HDd;

    k_embed<<<Tt, 256, 0, stream>>>(ids, emb, x);
    k_rope_tables<<<Ss, 64, 0, stream>>>(cosb, sinb);

    dim3 blk(TS, TS);
    for (int l = 0; l < NLAY; ++l) {
        k_rmsnorm<<<Tt, 64, 0, stream>>>(x, ln1_w + (size_t)l * Dm, h);
        k_gemm<<<dim3((QKVW + TS - 1) / TS, (Tt + TS - 1) / TS), blk, 0, stream>>>(
            h, qkv_w + (size_t)l * QKVW * Dm, nullptr, qkv, Tt, QKVW, Dm);
        k_rope<<<Tt, 256, 0, stream>>>(qkv, cosb, sinb);
        k_attn<<<dim3(Ss, NHh, Bb), 256, 0, stream>>>(qkv, aout);
        k_gemm<<<dim3((Dm + TS - 1) / TS, (Tt + TS - 1) / TS), blk, 0, stream>>>(
            aout, o_w + (size_t)l * Dm * Dm, x, x, Tt, Dm, Dm);
        k_rmsnorm<<<Tt, 64, 0, stream>>>(x, ln2_w + (size_t)l * Dm, h);
        k_gateup<<<dim3((FFf + TS - 1) / TS, (Tt + TS - 1) / TS), blk, 0, stream>>>(
            h, gate_w + (size_t)l * FFf * Dm, up_w + (size_t)l * FFf * Dm, act, Tt, FFf, Dm);
        k_gemm<<<dim3((Dm + TS - 1) / TS, (Tt + TS - 1) / TS), blk, 0, stream>>>(
            act, down_w + (size_t)l * Dm * FFf, x, x, Tt, Dm, FFf);
    }
    k_rmsnorm<<<Tt, 64, 0, stream>>>(x, norm_w, h);
    k_gemm<<<dim3((Vv + TS - 1) / TS, (Tt + TS - 1) / TS), blk, 0, stream>>>(
        h, lm_w, nullptr, out, Tt, Vv, Dm);
}

// Round 2
// 4514.970 us; speedup vs baseline: 1.5899x; 1.5899x over previous
//
#include <hip/hip_runtime.h>
#include <math.h>

#define Vv 32000
#define Dm 216
#define NLAY 11
#define NHh 4
#define HDd 54
#define FFf 864
#define Bb 2
#define Ss 1024
#define Tt (Bb*Ss)
#define EPSf 1e-5f
#define QKVW 648   // 3*Dm
#define KP 224     // K=216 padded to multiple of 32
#define GUN 1728   // gate+up concat N

typedef __attribute__((ext_vector_type(8))) short short8;
typedef __attribute__((ext_vector_type(8))) unsigned short ushort8;
typedef __attribute__((ext_vector_type(4))) float f32x4;

__device__ __forceinline__ unsigned short f2bf(float f) {
    unsigned int u = __float_as_uint(f);
    return (unsigned short)((u + 0x7fffu + ((u >> 16) & 1u)) >> 16);
}

// ---------------- embed gather ----------------
__global__ void k_embed(const int* __restrict__ ids, const float* __restrict__ emb,
                        float* __restrict__ x) {
    int t = blockIdx.x;
    int id = ids[t];
    for (int d = threadIdx.x; d < Dm; d += blockDim.x)
        x[(size_t)t * Dm + d] = emb[(size_t)id * Dm + d];
}

// ---------------- rope tables ----------------
__global__ void k_rope_tables(float* __restrict__ cosb, float* __restrict__ sinb) {
    int s = blockIdx.x;
    for (int d = threadIdx.x; d < HDd; d += blockDim.x) {
        int j = d % (HDd / 2);
        float inv = powf(10000.0f, -2.0f * (float)j / (float)HDd);
        float f = (float)s * inv;
        cosb[s * HDd + d] = cosf(f);
        sinb[s * HDd + d] = sinf(f);
    }
}

// ---------------- weight fp32 -> bf16 (padded) ----------------
__global__ void k_convw(const float* __restrict__ src, unsigned short* __restrict__ dst,
                        int L, int N, int K, int Npad, int Kp,
                        long dls, long doff) {
    size_t total = (size_t)L * Npad * Kp;
    for (size_t idx = (size_t)blockIdx.x * blockDim.x + threadIdx.x; idx < total;
         idx += (size_t)gridDim.x * blockDim.x) {
        int k = (int)(idx % Kp);
        size_t r = idx / Kp;
        int n = (int)(r % Npad);
        int l = (int)(r / Npad);
        float v = (n < N && k < K) ? src[((size_t)l * N + n) * K + k] : 0.f;
        dst[(size_t)l * dls + doff + (size_t)n * Kp + k] = f2bf(v);
    }
}

// ---------------- rmsnorm -> bf16 (K-padded with zeros) ----------------
__global__ void k_rmsnorm_bf(const float* __restrict__ x, const float* __restrict__ w,
                             unsigned short* __restrict__ h) {
    int t = blockIdx.x;
    const float* xr = x + (size_t)t * Dm;
    float ss = 0.f;
    for (int d = threadIdx.x; d < Dm; d += 64) { float v = xr[d]; ss += v * v; }
    for (int o = 32; o; o >>= 1) ss += __shfl_down(ss, o, 64);
    float r = __shfl(ss, 0, 64);
    r = rsqrtf(r / (float)Dm + EPSf);
    for (int d = threadIdx.x; d < KP; d += 64)
        h[(size_t)t * KP + d] = (d < Dm) ? f2bf(xr[d] * r * w[d]) : (unsigned short)0;
}

// ---------------- MFMA GEMM: out[m,n] = (res?) + sum_k A[m,k]*W[n,k] ----------------
// A: [2048][Kp] bf16, W: [gridDim.y*128][Kp] bf16 (zero-padded), out fp32 [2048][N]
// 128x128 tile, BK=32, 4 waves each 64x64 (4x4 frags of 16x16x32).
// LDS in fragment order: subtile (16 rows x 32 cols) stored as 64 chunks of 16B,
// chunk index = (kchunk<<4)|(row&15)  -> frag read is lds_base + lane*16 (conflict-free).
__global__ __launch_bounds__(256, 2) void k_mfma_gemm(
    const unsigned short* __restrict__ A, const unsigned short* __restrict__ W,
    const float* __restrict__ res, float* __restrict__ out,
    int N, int Kp)
{
    __shared__ __align__(16) unsigned short lds[2][2][4096];
    const int tid = threadIdx.x;
    const int m0 = blockIdx.x * 128;
    const int n0 = blockIdx.y * 128;
    const int wid = tid >> 6, lane = tid & 63;
    const int wr = wid >> 1, wc = wid & 1;
    const int nsteps = Kp >> 5;

    const int i0 = tid, i1 = tid + 256;
    const int rA0 = i0 >> 2, cA0 = i0 & 3;
    const int rA1 = i1 >> 2, cA1 = i1 & 3;
    const int lo0 = (rA0 >> 4) * 512 + (((cA0 << 4) | (rA0 & 15)) << 3);
    const int lo1 = (rA1 >> 4) * 512 + (((cA1 << 4) | (rA1 & 15)) << 3);

    ushort8 ra0, ra1, rb0, rb1;
    ra0 = *(const ushort8*)(A + (size_t)(m0 + rA0) * Kp + cA0 * 8);
    ra1 = *(const ushort8*)(A + (size_t)(m0 + rA1) * Kp + cA1 * 8);
    rb0 = *(const ushort8*)(W + (size_t)(n0 + rA0) * Kp + cA0 * 8);
    rb1 = *(const ushort8*)(W + (size_t)(n0 + rA1) * Kp + cA1 * 8);
    *(ushort8*)&lds[0][0][lo0] = ra0;
    *(ushort8*)&lds[0][0][lo1] = ra1;
    *(ushort8*)&lds[0][1][lo0] = rb0;
    *(ushort8*)&lds[0][1][lo1] = rb1;
    __syncthreads();

    f32x4 acc[4][4] = {};

    int cur = 0;
    for (int step = 0; step < nsteps; ++step) {
        const bool more = (step + 1) < nsteps;
        if (more) {
            const int k0 = (step + 1) << 5;
            ra0 = *(const ushort8*)(A + (size_t)(m0 + rA0) * Kp + k0 + cA0 * 8);
            ra1 = *(const ushort8*)(A + (size_t)(m0 + rA1) * Kp + k0 + cA1 * 8);
            rb0 = *(const ushort8*)(W + (size_t)(n0 + rA0) * Kp + k0 + cA0 * 8);
            rb1 = *(const ushort8*)(W + (size_t)(n0 + rA1) * Kp + k0 + cA1 * 8);
        }
        short8 af[4], bf[4];
        #pragma unroll
        for (int f = 0; f < 4; ++f) {
            af[f] = *(const short8*)&lds[cur][0][(wr * 4 + f) * 512 + lane * 8];
            bf[f] = *(const short8*)&lds[cur][1][(wc * 4 + f) * 512 + lane * 8];
        }
        #pragma unroll
        for (int fm = 0; fm < 4; ++fm)
            #pragma unroll
            for (int fn = 0; fn < 4; ++fn)
                acc[fm][fn] = __builtin_amdgcn_mfma_f32_16x16x32_bf16(af[fm], bf[fn], acc[fm][fn], 0, 0, 0);
        if (more) {
            const int nxt = cur ^ 1;
            *(ushort8*)&lds[nxt][0][lo0] = ra0;
            *(ushort8*)&lds[nxt][0][lo1] = ra1;
            *(ushort8*)&lds[nxt][1][lo0] = rb0;
            *(ushort8*)&lds[nxt][1][lo1] = rb1;
            __syncthreads();
            cur = nxt;
        }
    }

    #pragma unroll
    for (int fm = 0; fm < 4; ++fm) {
        const int mrow = m0 + wr * 64 + fm * 16 + (lane >> 4) * 4;
        #pragma unroll
        for (int fn = 0; fn < 4; ++fn) {
            const int ncol = n0 + wc * 64 + fn * 16 + (lane & 15);
            if (ncol < N) {
                #pragma unroll
                for (int i = 0; i < 4; ++i) {
                    const size_t oi = (size_t)(mrow + i) * N + ncol;
                    float v = acc[fm][fn][i];
                    if (res) v += res[oi];
                    out[oi] = v;
                }
            }
        }
    }
}

// ---------------- SiLU(gate)*up -> bf16 ----------------
__global__ void k_silu(const float* __restrict__ gu, unsigned short* __restrict__ act) {
    int i = blockIdx.x * 256 + threadIdx.x;
    if (i >= Tt * FFf) return;
    int m = i / FFf, f = i % FFf;
    float g = gu[(size_t)m * GUN + f];
    float u = gu[(size_t)m * GUN + FFf + f];
    act[i] = f2bf(u * g / (1.f + expf(-g)));
}

// ---------------- in-place RoPE on q,k halves of qkv ----------------
__global__ void k_rope(float* __restrict__ qkv, const float* __restrict__ cosb,
                       const float* __restrict__ sinb) {
    const int t = blockIdx.x;
    const int s = t % Ss;
    float* base = qkv + (size_t)t * QKVW;
    const int HALF = HDd / 2;
    int i = threadIdx.x;
    if (i < 2 * NHh * HALF) {
        int which = i / (NHh * HALF);
        int rem = i % (NHh * HALF);
        int hh = rem / HALF;
        int d = rem % HALF;
        float* ptr = base + which * Dm + hh * HDd;
        float x1 = ptr[d], x2 = ptr[d + HALF];
        float c1 = cosb[s * HDd + d], s1 = sinb[s * HDd + d];
        float c2 = cosb[s * HDd + d + HALF], s2 = sinb[s * HDd + d + HALF];
        ptr[d]        = x1 * c1 - x2 * s1;
        ptr[d + HALF] = x2 * c2 + x1 * s2;
    }
}

// ---------------- attention (fp32 math, bf16 out), wave-parallel PV ----------------
__global__ void k_attn_bf(const float* __restrict__ qkv, unsigned short* __restrict__ aout) {
    const int q = blockIdx.x, h = blockIdx.y, b = blockIdx.z;
    const int tid = threadIdx.x;
    __shared__ float p[Ss];
    __shared__ float qv[HDd];
    __shared__ float vacc[4][64];
    __shared__ float rmax[4], rsum[4];
    const size_t bbase = (size_t)b * Ss * QKVW;
    const float* qrow = qkv + bbase + (size_t)q * QKVW + h * HDd;
    if (tid < HDd) qv[tid] = qrow[tid];
    __syncthreads();
    const int nk = q + 1;
    const float scale = 0.13608276348795434f;
    float lmax = -3.0e38f;
    for (int k = tid; k < nk; k += 256) {
        const float* krow = qkv + bbase + (size_t)k * QKVW + Dm + h * HDd;
        float acc = 0.f;
        #pragma unroll
        for (int d = 0; d < HDd; ++d) acc += qv[d] * krow[d];
        acc *= scale;
        p[k] = acc;
        lmax = fmaxf(lmax, acc);
    }
    for (int o = 32; o; o >>= 1) lmax = fmaxf(lmax, __shfl_down(lmax, o, 64));
    if ((tid & 63) == 0) rmax[tid >> 6] = lmax;
    __syncthreads();
    const float m = fmaxf(fmaxf(rmax[0], rmax[1]), fmaxf(rmax[2], rmax[3]));
    float lsum = 0.f;
    for (int k = tid; k < nk; k += 256) {
        float e = expf(p[k] - m);
        p[k] = e;
        lsum += e;
    }
    for (int o = 32; o; o >>= 1) lsum += __shfl_down(lsum, o, 64);
    if ((tid & 63) == 0) rsum[tid >> 6] = lsum;
    __syncthreads();
    const float inv = 1.f / (rsum[0] + rsum[1] + rsum[2] + rsum[3]);
    const int w = tid >> 6, lane = tid & 63;
    float a = 0.f;
    const float* vbase = qkv + bbase + 2 * Dm + h * HDd;
    if (lane < HDd)
        for (int k = w; k < nk; k += 4)
            a += p[k] * vbase[(size_t)k * QKVW + lane];
    vacc[w][lane] = a;
    __syncthreads();
    const size_t orow = (size_t)(b * Ss + q) * KP;
    if (tid < HDd)
        aout[orow + h * HDd + tid] =
            f2bf((vacc[0][tid] + vacc[1][tid] + vacc[2][tid] + vacc[3][tid]) * inv);
    if (h == 0 && tid < KP - Dm) aout[orow + Dm + tid] = 0;
}

// ================= legacy fp32 fallback kernels (round-0) =================
__global__ void k_rmsnorm(const float* __restrict__ x, const float* __restrict__ w,
                          float* __restrict__ h) {
    int t = blockIdx.x;
    const float* xr = x + (size_t)t * Dm;
    float ss = 0.f;
    for (int d = threadIdx.x; d < Dm; d += 64) { float v = xr[d]; ss += v * v; }
    for (int o = 32; o; o >>= 1) ss += __shfl_down(ss, o, 64);
    float r = __shfl(ss, 0, 64);
    r = rsqrtf(r / (float)Dm + EPSf);
    for (int d = threadIdx.x; d < Dm; d += 64)
        h[(size_t)t * Dm + d] = xr[d] * r * w[d];
}

#define TS 16
__global__ void k_gemm(const float* __restrict__ A, const float* __restrict__ W,
                       const float* __restrict__ res, float* __restrict__ out,
                       int M, int N, int K) {
    __shared__ float As[TS][TS + 1];
    __shared__ float Wsm[TS][TS + 1];
    const int tx = threadIdx.x, ty = threadIdx.y;
    const int m = blockIdx.y * TS + ty;
    const int n = blockIdx.x * TS + tx;
    float acc = 0.f;
    for (int k0 = 0; k0 < K; k0 += TS) {
        int ka = k0 + tx;
        As[ty][tx] = (m < M && ka < K) ? A[(size_t)m * K + ka] : 0.f;
        int nw = blockIdx.x * TS + ty;
        Wsm[ty][tx] = (nw < N && ka < K) ? W[(size_t)nw * K + ka] : 0.f;
        __syncthreads();
        #pragma unroll
        for (int kk = 0; kk < TS; ++kk) acc += As[ty][kk] * Wsm[tx][kk];
        __syncthreads();
    }
    if (m < M && n < N) {
        float r = res ? res[(size_t)m * N + n] : 0.f;
        out[(size_t)m * N + n] = r + acc;
    }
}

__global__ void k_gateup(const float* __restrict__ A, const float* __restrict__ Wg,
                         const float* __restrict__ Wu, float* __restrict__ act,
                         int M, int N, int K) {
    __shared__ float As[TS][TS + 1];
    __shared__ float Gs[TS][TS + 1];
    __shared__ float Us[TS][TS + 1];
    const int tx = threadIdx.x, ty = threadIdx.y;
    const int m = blockIdx.y * TS + ty;
    const int n = blockIdx.x * TS + tx;
    float ag = 0.f, au = 0.f;
    for (int k0 = 0; k0 < K; k0 += TS) {
        int ka = k0 + tx;
        As[ty][tx] = (m < M && ka < K) ? A[(size_t)m * K + ka] : 0.f;
        int nw = blockIdx.x * TS + ty;
        Gs[ty][tx] = (nw < N && ka < K) ? Wg[(size_t)nw * K + ka] : 0.f;
        Us[ty][tx] = (nw < N && ka < K) ? Wu[(size_t)nw * K + ka] : 0.f;
        __syncthreads();
        #pragma unroll
        for (int kk = 0; kk < TS; ++kk) {
            ag += As[ty][kk] * Gs[tx][kk];
            au += As[ty][kk] * Us[tx][kk];
        }
        __syncthreads();
    }
    if (m < M && n < N) {
        float sg = ag / (1.f + expf(-ag));
        act[(size_t)m * N + n] = sg * au;
    }
}

__global__ void k_attn(const float* __restrict__ qkv, float* __restrict__ aout) {
    const int q = blockIdx.x, h = blockIdx.y, b = blockIdx.z;
    const int tid = threadIdx.x;
    __shared__ float p[Ss];
    __shared__ float qv[HDd];
    __shared__ float rmax[4], rsum[4];
    const size_t base = (size_t)b * Ss * QKVW;
    const float* qrow = qkv + base + (size_t)q * QKVW + h * HDd;
    if (tid < HDd) qv[tid] = qrow[tid];
    __syncthreads();
    const int nk = q + 1;
    const float scale = 0.13608276348795434f;
    float lmax = -3.0e38f;
    for (int k = tid; k < nk; k += 256) {
        const float* krow = qkv + base + (size_t)k * QKVW + Dm + h * HDd;
        float acc = 0.f;
        #pragma unroll
        for (int d = 0; d < HDd; ++d) acc += qv[d] * krow[d];
        acc *= scale;
        p[k] = acc;
        lmax = fmaxf(lmax, acc);
    }
    for (int o = 32; o; o >>= 1) lmax = fmaxf(lmax, __shfl_down(lmax, o, 64));
    if ((tid & 63) == 0) rmax[tid >> 6] = lmax;
    __syncthreads();
    const float m = fmaxf(fmaxf(rmax[0], rmax[1]), fmaxf(rmax[2], rmax[3]));
    float lsum = 0.f;
    for (int k = tid; k < nk; k += 256) {
        float e = expf(p[k] - m);
        p[k] = e;
        lsum += e;
    }
    for (int o = 32; o; o >>= 1) lsum += __shfl_down(lsum, o, 64);
    if ((tid & 63) == 0) rsum[tid >> 6] = lsum;
    __syncthreads();
    const float inv = 1.f / (rsum[0] + rsum[1] + rsum[2] + rsum[3]);
    for (int d = tid; d < HDd; d += 256) {
        const float* vcol = qkv + base + 2 * Dm + h * HDd + d;
        float acc = 0.f;
        for (int k = 0; k < nk; ++k) acc += p[k] * vcol[(size_t)k * QKVW];
        aout[(size_t)(b * Ss + q) * Dm + h * HDd + d] = acc * inv;
    }
}

// =====================================================================
extern "C" void kernel_launch(void* const* d_in, const int* in_sizes, int n_in,
                              void* d_out, int out_size, void* d_ws, size_t ws_size,
                              hipStream_t stream) {
    const int*   ids    = (const int*)d_in[0];
    const float* emb    = (const float*)d_in[1];
    const float* ln1_w  = (const float*)d_in[2];
    const float* qkv_w  = (const float*)d_in[3];
    const float* o_w    = (const float*)d_in[4];
    const float* ln2_w  = (const float*)d_in[5];
    const float* gate_w = (const float*)d_in[6];
    const float* up_w   = (const float*)d_in[7];
    const float* down_w = (const float*)d_in[8];
    const float* norm_w = (const float*)d_in[9];
    const float* lm_w   = (const float*)d_in[10];
    float* out = (float*)d_out;

    char* base = (char*)d_ws;
    size_t off = 0;
    auto carve = [&](size_t bytes) -> char* {
        char* p = base + off;
        off += (bytes + 255) & ~(size_t)255;
        return p;
    };

    // fp32 buffers
    float* x    = (float*)carve((size_t)Tt * Dm * 4);
    float* qkv  = (float*)carve((size_t)Tt * QKVW * 4);
    float* gu   = (float*)carve((size_t)Tt * GUN * 4);
    float* cosb = (float*)carve((size_t)Ss * HDd * 4);
    float* sinb = (float*)carve((size_t)Ss * HDd * 4);
    // bf16 buffers
    unsigned short* h    = (unsigned short*)carve((size_t)Tt * KP * 2);
    unsigned short* aout = (unsigned short*)carve((size_t)Tt * KP * 2);
    unsigned short* act  = (unsigned short*)carve((size_t)Tt * FFf * 2);
    unsigned short* qkvw = (unsigned short*)carve((size_t)NLAY * 768 * KP * 2);
    unsigned short* ow   = (unsigned short*)carve((size_t)NLAY * 256 * KP * 2);
    unsigned short* guw  = (unsigned short*)carve((size_t)NLAY * 1792 * KP * 2);
    unsigned short* dww  = (unsigned short*)carve((size_t)NLAY * 256 * 864 * 2);
    unsigned short* lmw  = (unsigned short*)carve((size_t)Vv * KP * 2);
    size_t need = off;

    if (ws_size >= need) {
        // -------- bf16 MFMA path --------
        k_embed<<<Tt, 256, 0, stream>>>(ids, emb, x);
        k_rope_tables<<<Ss, 64, 0, stream>>>(cosb, sinb);

        k_convw<<<512, 256, 0, stream>>>(qkv_w, qkvw, NLAY, QKVW, Dm, 768, KP, 768L * KP, 0);
        k_convw<<<256, 256, 0, stream>>>(o_w,   ow,   NLAY, Dm,   Dm, 256, KP, 256L * KP, 0);
        k_convw<<<512, 256, 0, stream>>>(gate_w, guw, NLAY, FFf,  Dm, 864, KP, 1792L * KP, 0);
        k_convw<<<512, 256, 0, stream>>>(up_w,   guw, NLAY, FFf,  Dm, 928, KP, 1792L * KP, 864L * KP);
        k_convw<<<512, 256, 0, stream>>>(down_w, dww, NLAY, Dm,  FFf, 256, 864, 256L * 864, 0);
        k_convw<<<1024, 256, 0, stream>>>(lm_w,  lmw, 1,    Vv,   Dm, Vv,  KP, (long)Vv * KP, 0);

        for (int l = 0; l < NLAY; ++l) {
            k_rmsnorm_bf<<<Tt, 64, 0, stream>>>(x, ln1_w + (size_t)l * Dm, h);
            k_mfma_gemm<<<dim3(16, 6), 256, 0, stream>>>(h, qkvw + (size_t)l * 768 * KP,
                                                         nullptr, qkv, QKVW, KP);
            k_rope<<<Tt, 256, 0, stream>>>(qkv, cosb, sinb);
            k_attn_bf<<<dim3(Ss, NHh, Bb), 256, 0, stream>>>(qkv, aout);
            k_mfma_gemm<<<dim3(16, 2), 256, 0, stream>>>(aout, ow + (size_t)l * 256 * KP,
                                                         x, x, Dm, KP);
            k_rmsnorm_bf<<<Tt, 64, 0, stream>>>(x, ln2_w + (size_t)l * Dm, h);
            k_mfma_gemm<<<dim3(16, 14), 256, 0, stream>>>(h, guw + (size_t)l * 1792 * KP,
                                                          nullptr, gu, GUN, KP);
            k_silu<<<(Tt * FFf + 255) / 256, 256, 0, stream>>>(gu, act);
            k_mfma_gemm<<<dim3(16, 2), 256, 0, stream>>>(act, dww + (size_t)l * 256 * 864,
                                                         x, x, Dm, 864);
        }
        k_rmsnorm_bf<<<Tt, 64, 0, stream>>>(x, norm_w, h);
        k_mfma_gemm<<<dim3(16, 250), 256, 0, stream>>>(h, lmw, nullptr, out, Vv, KP);
    } else {
        // -------- legacy fp32 fallback --------
        float* ws = (float*)d_ws;
        size_t o2 = 0;
        float* x2    = ws + o2; o2 += (size_t)Tt * Dm;
        float* h2    = ws + o2; o2 += (size_t)Tt * Dm;
        float* qkv2  = ws + o2; o2 += (size_t)Tt * QKVW;
        float* aout2 = ws + o2; o2 += (size_t)Tt * Dm;
        float* act2  = ws + o2; o2 += (size_t)Tt * FFf;
        float* cosb2 = ws + o2; o2 += (size_t)Ss * HDd;
        float* sinb2 = ws + o2; o2 += (size_t)Ss * HDd;

        k_embed<<<Tt, 256, 0, stream>>>(ids, emb, x2);
        k_rope_tables<<<Ss, 64, 0, stream>>>(cosb2, sinb2);
        dim3 blk(TS, TS);
        for (int l = 0; l < NLAY; ++l) {
            k_rmsnorm<<<Tt, 64, 0, stream>>>(x2, ln1_w + (size_t)l * Dm, h2);
            k_gemm<<<dim3((QKVW + TS - 1) / TS, (Tt + TS - 1) / TS), blk, 0, stream>>>(
                h2, qkv_w + (size_t)l * QKVW * Dm, nullptr, qkv2, Tt, QKVW, Dm);
            k_rope<<<Tt, 256, 0, stream>>>(qkv2, cosb2, sinb2);
            k_attn<<<dim3(Ss, NHh, Bb), 256, 0, stream>>>(qkv2, aout2);
            k_gemm<<<dim3((Dm + TS - 1) / TS, (Tt + TS - 1) / TS), blk, 0, stream>>>(
                aout2, o_w + (size_t)l * Dm * Dm, x2, x2, Tt, Dm, Dm);
            k_rmsnorm<<<Tt, 64, 0, stream>>>(x2, ln2_w + (size_t)l * Dm, h2);
            k_gateup<<<dim3((FFf + TS - 1) / TS, (Tt + TS - 1) / TS), blk, 0, stream>>>(
                h2, gate_w + (size_t)l * FFf * Dm, up_w + (size_t)l * FFf * Dm, act2, Tt, FFf, Dm);
            k_gemm<<<dim3((Dm + TS - 1) / TS, (Tt + TS - 1) / TS), blk, 0, stream>>>(
                act2, down_w + (size_t)l * Dm * FFf, x2, x2, Tt, Dm, FFf);
        }
        k_rmsnorm<<<Tt, 64, 0, stream>>>(x2, norm_w, h2);
        k_gemm<<<dim3((Vv + TS - 1) / TS, (Tt + TS - 1) / TS), blk, 0, stream>>>(
            h2, lm_w, nullptr, out, Tt, Vv, Dm);
    }
}

// Round 4
// 1897.467 us; speedup vs baseline: 3.7830x; 2.3795x over previous
//
#include <hip/hip_runtime.h>
#include <math.h>

#define Vv 32000
#define Dm 216
#define NLAY 11
#define NHh 4
#define HDd 54
#define FFf 864
#define Bb 2
#define Ss 1024
#define Tt (Bb*Ss)
#define EPSf 1e-5f
#define QKVW 648   // 3*Dm
#define KP 224     // K=216 padded to multiple of 32
#define GUN 1728   // gate+up concat N
#define HDP 64     // head dim padded
#define VTSZ (Ss*HDP)

typedef __attribute__((ext_vector_type(8))) short short8;
typedef __attribute__((ext_vector_type(8))) unsigned short ushort8;
typedef __attribute__((ext_vector_type(4))) float f32x4;

__device__ __forceinline__ unsigned short f2bf(float f) {
    unsigned int u = __float_as_uint(f);
    return (unsigned short)((u + 0x7fffu + ((u >> 16) & 1u)) >> 16);
}

// ---------------- embed gather ----------------
__global__ void k_embed(const int* __restrict__ ids, const float* __restrict__ emb,
                        float* __restrict__ x) {
    int t = blockIdx.x;
    int id = ids[t];
    for (int d = threadIdx.x; d < Dm; d += blockDim.x)
        x[(size_t)t * Dm + d] = emb[(size_t)id * Dm + d];
}

// ---------------- rope tables ----------------
__global__ void k_rope_tables(float* __restrict__ cosb, float* __restrict__ sinb) {
    int s = blockIdx.x;
    for (int d = threadIdx.x; d < HDd; d += blockDim.x) {
        int j = d % (HDd / 2);
        float inv = powf(10000.0f, -2.0f * (float)j / (float)HDd);
        float f = (float)s * inv;
        cosb[s * HDd + d] = cosf(f);
        sinb[s * HDd + d] = sinf(f);
    }
}

// ---------------- weight fp32 -> bf16 (padded) ----------------
__global__ void k_convw(const float* __restrict__ src, unsigned short* __restrict__ dst,
                        int L, int N, int K, int Npad, int Kp,
                        long dls, long doff) {
    size_t total = (size_t)L * Npad * Kp;
    for (size_t idx = (size_t)blockIdx.x * blockDim.x + threadIdx.x; idx < total;
         idx += (size_t)gridDim.x * blockDim.x) {
        int k = (int)(idx % Kp);
        size_t r = idx / Kp;
        int n = (int)(r % Npad);
        int l = (int)(r / Npad);
        float v = (n < N && k < K) ? src[((size_t)l * N + n) * K + k] : 0.f;
        dst[(size_t)l * dls + doff + (size_t)n * Kp + k] = f2bf(v);
    }
}

// ---------------- rmsnorm -> bf16 (K-padded with zeros) ----------------
__global__ void k_rmsnorm_bf(const float* __restrict__ x, const float* __restrict__ w,
                             unsigned short* __restrict__ h) {
    int t = blockIdx.x;
    const float* xr = x + (size_t)t * Dm;
    float ss = 0.f;
    for (int d = threadIdx.x; d < Dm; d += 64) { float v = xr[d]; ss += v * v; }
    for (int o = 32; o; o >>= 1) ss += __shfl_down(ss, o, 64);
    float r = __shfl(ss, 0, 64);
    r = rsqrtf(r / (float)Dm + EPSf);
    for (int d = threadIdx.x; d < KP; d += 64)
        h[(size_t)t * KP + d] = (d < Dm) ? f2bf(xr[d] * r * w[d]) : (unsigned short)0;
}

// ---------------- MFMA GEMM (128x128 tile, BK=32, dbuf) ----------------
__global__ __launch_bounds__(256, 2) void k_mfma_gemm(
    const unsigned short* __restrict__ A, const unsigned short* __restrict__ W,
    const float* __restrict__ res, float* __restrict__ out,
    int N, int Kp)
{
    __shared__ __align__(16) unsigned short lds[2][2][4096];
    const int tid = threadIdx.x;
    const int m0 = blockIdx.x * 128;
    const int n0 = blockIdx.y * 128;
    const int wid = tid >> 6, lane = tid & 63;
    const int wr = wid >> 1, wc = wid & 1;
    const int nsteps = Kp >> 5;

    const int i0 = tid, i1 = tid + 256;
    const int rA0 = i0 >> 2, cA0 = i0 & 3;
    const int rA1 = i1 >> 2, cA1 = i1 & 3;
    const int lo0 = (rA0 >> 4) * 512 + (((cA0 << 4) | (rA0 & 15)) << 3);
    const int lo1 = (rA1 >> 4) * 512 + (((cA1 << 4) | (rA1 & 15)) << 3);

    ushort8 ra0, ra1, rb0, rb1;
    ra0 = *(const ushort8*)(A + (size_t)(m0 + rA0) * Kp + cA0 * 8);
    ra1 = *(const ushort8*)(A + (size_t)(m0 + rA1) * Kp + cA1 * 8);
    rb0 = *(const ushort8*)(W + (size_t)(n0 + rA0) * Kp + cA0 * 8);
    rb1 = *(const ushort8*)(W + (size_t)(n0 + rA1) * Kp + cA1 * 8);
    *(ushort8*)&lds[0][0][lo0] = ra0;
    *(ushort8*)&lds[0][0][lo1] = ra1;
    *(ushort8*)&lds[0][1][lo0] = rb0;
    *(ushort8*)&lds[0][1][lo1] = rb1;
    __syncthreads();

    f32x4 acc[4][4] = {};

    int cur = 0;
    for (int step = 0; step < nsteps; ++step) {
        const bool more = (step + 1) < nsteps;
        if (more) {
            const int k0 = (step + 1) << 5;
            ra0 = *(const ushort8*)(A + (size_t)(m0 + rA0) * Kp + k0 + cA0 * 8);
            ra1 = *(const ushort8*)(A + (size_t)(m0 + rA1) * Kp + k0 + cA1 * 8);
            rb0 = *(const ushort8*)(W + (size_t)(n0 + rA0) * Kp + k0 + cA0 * 8);
            rb1 = *(const ushort8*)(W + (size_t)(n0 + rA1) * Kp + k0 + cA1 * 8);
        }
        short8 af[4], bf[4];
        #pragma unroll
        for (int f = 0; f < 4; ++f) {
            af[f] = *(const short8*)&lds[cur][0][(wr * 4 + f) * 512 + lane * 8];
            bf[f] = *(const short8*)&lds[cur][1][(wc * 4 + f) * 512 + lane * 8];
        }
        #pragma unroll
        for (int fm = 0; fm < 4; ++fm)
            #pragma unroll
            for (int fn = 0; fn < 4; ++fn)
                acc[fm][fn] = __builtin_amdgcn_mfma_f32_16x16x32_bf16(af[fm], bf[fn], acc[fm][fn], 0, 0, 0);
        if (more) {
            const int nxt = cur ^ 1;
            *(ushort8*)&lds[nxt][0][lo0] = ra0;
            *(ushort8*)&lds[nxt][0][lo1] = ra1;
            *(ushort8*)&lds[nxt][1][lo0] = rb0;
            *(ushort8*)&lds[nxt][1][lo1] = rb1;
            __syncthreads();
            cur = nxt;
        }
    }

    #pragma unroll
    for (int fm = 0; fm < 4; ++fm) {
        const int mrow = m0 + wr * 64 + fm * 16 + (lane >> 4) * 4;
        #pragma unroll
        for (int fn = 0; fn < 4; ++fn) {
            const int ncol = n0 + wc * 64 + fn * 16 + (lane & 15);
            if (ncol < N) {
                #pragma unroll
                for (int i = 0; i < 4; ++i) {
                    const size_t oi = (size_t)(mrow + i) * N + ncol;
                    float v = acc[fm][fn][i];
                    if (res) v += res[oi];
                    out[oi] = v;
                }
            }
        }
    }
}

// ---------------- SiLU(gate)*up -> bf16 ----------------
__global__ void k_silu(const float* __restrict__ gu, unsigned short* __restrict__ act) {
    int i = blockIdx.x * 256 + threadIdx.x;
    if (i >= Tt * FFf) return;
    int m = i / FFf, f = i % FFf;
    float g = gu[(size_t)m * GUN + f];
    float u = gu[(size_t)m * GUN + FFf + f];
    act[i] = f2bf(u * g / (1.f + expf(-g)));
}

// ---------------- prep: qkv fp32 -> Qb,Kb bf16 [bh][S][64] with RoPE ----------------
__global__ void k_prep_qk(const float* __restrict__ qkv, const float* __restrict__ cosb,
                          const float* __restrict__ sinb,
                          unsigned short* __restrict__ Qb, unsigned short* __restrict__ Kb) {
    const int t = blockIdx.x;
    const int b = t >> 10, s = t & 1023;
    const int i = threadIdx.x;
    const float scale = 0.13608276348795434f; // 54^-0.5, folded into Q
    if (i < 216) {
        int which = i / 108;            // 0=q, 1=k
        int r = i % 108;
        int h = r / 27, j = r % 27;
        const float* base = qkv + (size_t)t * QKVW + which * Dm + h * HDd;
        float x1 = base[j], x2 = base[j + 27];
        float c = cosb[s * HDd + j], sn = sinb[s * HDd + j];
        float o1 = x1 * c - x2 * sn;
        float o2 = x2 * c + x1 * sn;
        float sc = which ? 1.f : scale;
        unsigned short* dst = (which ? Kb : Qb) + ((size_t)(b * NHh + h) * Ss + s) * HDP;
        dst[j] = f2bf(o1 * sc);
        dst[j + 27] = f2bf(o2 * sc);
    } else {
        int z = i - 216; // 40 threads cover 80 pad slots (2 arrays x 4 h x 10 cols)
        for (int rep = 0; rep < 2; ++rep) {
            int idx = z * 2 + rep;
            int which = idx / 40;
            int r2 = idx % 40;
            int h = r2 / 10, d = 54 + r2 % 10;
            unsigned short* dst = (which ? Kb : Qb) + ((size_t)(b * NHh + h) * Ss + s) * HDP;
            dst[d] = 0;
        }
    }
}

// ---------------- prep: V transpose -> Vt bf16 [bh][64][S] ----------------
__global__ void k_prep_v(const float* __restrict__ qkv, unsigned short* __restrict__ Vt) {
    __shared__ __align__(16) unsigned short lv[64 * 72];
    const int s0 = blockIdx.x * 64;
    const int h = blockIdx.y, b = blockIdx.z;
    const int tid = threadIdx.x;
    for (int idx = tid; idx < 64 * 54; idx += 256) {
        int sr = idx / 54, d = idx % 54;
        float v = qkv[(size_t)(b * Ss + s0 + sr) * QKVW + 2 * Dm + h * HDd + d];
        lv[d * 72 + sr] = f2bf(v);
    }
    for (int idx = tid; idx < 64 * 10; idx += 256) {
        int d = 54 + (idx >> 6), sr = idx & 63;
        lv[d * 72 + sr] = 0;
    }
    __syncthreads();
    unsigned short* dstb = Vt + (size_t)(b * NHh + h) * VTSZ;
    for (int c = tid; c < 512; c += 256) {
        int d = c >> 3, sc = c & 7;
        *(ushort8*)(dstb + (size_t)d * Ss + s0 + sc * 8) = *(const ushort8*)&lv[d * 72 + sc * 8];
    }
}

// ---------------- MFMA flash attention ----------------
// grid (32 qblk, NHh, Bb), 128 threads (2 waves x 16 q-rows). KV tiles of 64.
__global__ __launch_bounds__(128) void k_attn_fa(
    const unsigned short* __restrict__ Qb, const unsigned short* __restrict__ Kb,
    const unsigned short* __restrict__ Vt, unsigned short* __restrict__ aout)
{
    __shared__ __align__(16) unsigned short Kl[4096];
    __shared__ __align__(16) unsigned short Vl[4096];
    __shared__ __align__(16) unsigned short Pl[2048];
    const int tid = threadIdx.x;
    const int qb = blockIdx.x, h = blockIdx.y, b = blockIdx.z;
    const int bh = b * NHh + h;
    const int q0 = qb * 32;
    const int w = tid >> 6, lane = tid & 63;
    const int q0w = q0 + w * 16;
    const int lc = lane & 15, lg = lane >> 4;

    if (h == 0) { // zero pad cols 216..223 of aout for this block's rows
        for (int idx = tid; idx < 32 * 8; idx += 128) {
            int r = idx >> 3, cpad = idx & 7;
            aout[(size_t)(b * Ss + q0 + r) * KP + Dm + cpad] = 0;
        }
    }

    const unsigned short* Qp = Qb + (size_t)bh * VTSZ;
    const unsigned short* Kpp = Kb + (size_t)bh * VTSZ;
    const unsigned short* Vp = Vt + (size_t)bh * VTSZ;

    short8 qa[2];
    #pragma unroll
    for (int half = 0; half < 2; ++half)
        qa[half] = *(const short8*)(Qp + (size_t)(q0w + lc) * HDP + lg * 8 + half * 32);

    f32x4 o4[4] = {};
    float mreg[4] = {-3e38f, -3e38f, -3e38f, -3e38f};
    float lreg[4] = {0.f, 0.f, 0.f, 0.f};

    const int nt = (q0 + 31) / 64 + 1;
    for (int t = 0; t < nt; ++t) {
        const int kv0 = t * 64;
        if (t) __syncthreads();
        for (int c = tid; c < 1024; c += 128) {
            if (c < 512) {
                int sub = c >> 6;
                int dhalf = sub >> 2, kgrp = sub & 3;
                int dchunk = (c >> 4) & 3, krow = c & 15;
                *(ushort8*)&Kl[sub * 512 + (c & 63) * 8] =
                    *(const ushort8*)(Kpp + (size_t)(kv0 + kgrp * 16 + krow) * HDP + dhalf * 32 + dchunk * 8);
            } else {
                int c2 = c - 512;
                int sub2 = c2 >> 6;
                int khalf = sub2 >> 2, dgrp = sub2 & 3;
                int kchunk = (c2 >> 4) & 3, drow = c2 & 15;
                *(ushort8*)&Vl[sub2 * 512 + (c2 & 63) * 8] =
                    *(const ushort8*)(Vp + (size_t)(dgrp * 16 + drow) * Ss + kv0 + khalf * 32 + kchunk * 8);
            }
        }
        __syncthreads();

        // QK^T: S[16q][64k]
        f32x4 s4[4] = {};
        #pragma unroll
        for (int half = 0; half < 2; ++half) {
            #pragma unroll
            for (int fn = 0; fn < 4; ++fn) {
                short8 kf = *(const short8*)&Kl[(half * 4 + fn) * 512 + lane * 8];
                s4[fn] = __builtin_amdgcn_mfma_f32_16x16x32_bf16(qa[half], kf, s4[fn], 0, 0, 0);
            }
        }
        // causal mask: needed whenever tile's max k exceeds wave's LOWEST q-row
        if (kv0 + 63 > q0w) {
            #pragma unroll
            for (int fn = 0; fn < 4; ++fn) {
                int kg = kv0 + fn * 16 + lc;
                #pragma unroll
                for (int r = 0; r < 4; ++r) {
                    int qg = q0w + lg * 4 + r;
                    if (kg > qg) s4[fn][r] = -3e38f;
                }
            }
        }
        // online softmax (each q-row lives in a 16-lane group)
        #pragma unroll
        for (int r = 0; r < 4; ++r) {
            float rm = fmaxf(fmaxf(s4[0][r], s4[1][r]), fmaxf(s4[2][r], s4[3][r]));
            #pragma unroll
            for (int msk = 1; msk < 16; msk <<= 1)
                rm = fmaxf(rm, __shfl_xor(rm, msk, 64));
            float mn = fmaxf(mreg[r], rm);
            float esc = __expf(mreg[r] - mn);
            mreg[r] = mn;
            float p0 = __expf(s4[0][r] - mn);
            float p1 = __expf(s4[1][r] - mn);
            float p2 = __expf(s4[2][r] - mn);
            float p3 = __expf(s4[3][r] - mn);
            float rs = p0 + p1 + p2 + p3;
            #pragma unroll
            for (int msk = 1; msk < 16; msk <<= 1)
                rs += __shfl_xor(rs, msk, 64);
            lreg[r] = lreg[r] * esc + rs;
            #pragma unroll
            for (int db = 0; db < 4; ++db) o4[db][r] *= esc;
            // write P to LDS in A-fragment order: chunk = (k>>3)*16 + q
            int q = lg * 4 + r;
            int kc = lc >> 3, ko = lc & 7;
            Pl[w * 1024 + ((0 * 2 + kc) * 16 + q) * 8 + ko] = f2bf(p0);
            Pl[w * 1024 + ((1 * 2 + kc) * 16 + q) * 8 + ko] = f2bf(p1);
            Pl[w * 1024 + ((2 * 2 + kc) * 16 + q) * 8 + ko] = f2bf(p2);
            Pl[w * 1024 + ((3 * 2 + kc) * 16 + q) * 8 + ko] = f2bf(p3);
        }
        // PV: O[16q][64d] += P[16q][64k] * V[64k][64d]
        short8 pa0 = *(const short8*)&Pl[w * 1024 + ((0 + lg) * 16 + lc) * 8];
        short8 pa1 = *(const short8*)&Pl[w * 1024 + ((4 + lg) * 16 + lc) * 8];
        #pragma unroll
        for (int db = 0; db < 4; ++db) {
            short8 vf0 = *(const short8*)&Vl[(0 + db) * 512 + lane * 8];
            o4[db] = __builtin_amdgcn_mfma_f32_16x16x32_bf16(pa0, vf0, o4[db], 0, 0, 0);
            short8 vf1 = *(const short8*)&Vl[(4 + db) * 512 + lane * 8];
            o4[db] = __builtin_amdgcn_mfma_f32_16x16x32_bf16(pa1, vf1, o4[db], 0, 0, 0);
        }
    }

    #pragma unroll
    for (int r = 0; r < 4; ++r) {
        float inv = 1.f / lreg[r];
        int row = b * Ss + q0w + lg * 4 + r;
        #pragma unroll
        for (int db = 0; db < 4; ++db) {
            int col = db * 16 + lc;
            if (col < HDd)
                aout[(size_t)row * KP + h * HDd + col] = f2bf(o4[db][r] * inv);
        }
    }
}

// ================= legacy fp32 fallback kernels =================
__global__ void k_rmsnorm(const float* __restrict__ x, const float* __restrict__ w,
                          float* __restrict__ h) {
    int t = blockIdx.x;
    const float* xr = x + (size_t)t * Dm;
    float ss = 0.f;
    for (int d = threadIdx.x; d < Dm; d += 64) { float v = xr[d]; ss += v * v; }
    for (int o = 32; o; o >>= 1) ss += __shfl_down(ss, o, 64);
    float r = __shfl(ss, 0, 64);
    r = rsqrtf(r / (float)Dm + EPSf);
    for (int d = threadIdx.x; d < Dm; d += 64)
        h[(size_t)t * Dm + d] = xr[d] * r * w[d];
}

#define TS 16
__global__ void k_gemm(const float* __restrict__ A, const float* __restrict__ W,
                       const float* __restrict__ res, float* __restrict__ out,
                       int M, int N, int K) {
    __shared__ float As[TS][TS + 1];
    __shared__ float Wsm[TS][TS + 1];
    const int tx = threadIdx.x, ty = threadIdx.y;
    const int m = blockIdx.y * TS + ty;
    const int n = blockIdx.x * TS + tx;
    float acc = 0.f;
    for (int k0 = 0; k0 < K; k0 += TS) {
        int ka = k0 + tx;
        As[ty][tx] = (m < M && ka < K) ? A[(size_t)m * K + ka] : 0.f;
        int nw = blockIdx.x * TS + ty;
        Wsm[ty][tx] = (nw < N && ka < K) ? W[(size_t)nw * K + ka] : 0.f;
        __syncthreads();
        #pragma unroll
        for (int kk = 0; kk < TS; ++kk) acc += As[ty][kk] * Wsm[tx][kk];
        __syncthreads();
    }
    if (m < M && n < N) {
        float r = res ? res[(size_t)m * N + n] : 0.f;
        out[(size_t)m * N + n] = r + acc;
    }
}

__global__ void k_gateup(const float* __restrict__ A, const float* __restrict__ Wg,
                         const float* __restrict__ Wu, float* __restrict__ act,
                         int M, int N, int K) {
    __shared__ float As[TS][TS + 1];
    __shared__ float Gs[TS][TS + 1];
    __shared__ float Us[TS][TS + 1];
    const int tx = threadIdx.x, ty = threadIdx.y;
    const int m = blockIdx.y * TS + ty;
    const int n = blockIdx.x * TS + tx;
    float ag = 0.f, au = 0.f;
    for (int k0 = 0; k0 < K; k0 += TS) {
        int ka = k0 + tx;
        As[ty][tx] = (m < M && ka < K) ? A[(size_t)m * K + ka] : 0.f;
        int nw = blockIdx.x * TS + ty;
        Gs[ty][tx] = (nw < N && ka < K) ? Wg[(size_t)nw * K + ka] : 0.f;
        Us[ty][tx] = (nw < N && ka < K) ? Wu[(size_t)nw * K + ka] : 0.f;
        __syncthreads();
        #pragma unroll
        for (int kk = 0; kk < TS; ++kk) {
            ag += As[ty][kk] * Gs[tx][kk];
            au += As[ty][kk] * Us[tx][kk];
        }
        __syncthreads();
    }
    if (m < M && n < N) {
        float sg = ag / (1.f + expf(-ag));
        act[(size_t)m * N + n] = sg * au;
    }
}

__global__ void k_rope(float* __restrict__ qkv, const float* __restrict__ cosb,
                       const float* __restrict__ sinb) {
    const int t = blockIdx.x;
    const int s = t % Ss;
    float* base = qkv + (size_t)t * QKVW;
    const int HALF = HDd / 2;
    int i = threadIdx.x;
    if (i < 2 * NHh * HALF) {
        int which = i / (NHh * HALF);
        int rem = i % (NHh * HALF);
        int hh = rem / HALF;
        int d = rem % HALF;
        float* ptr = base + which * Dm + hh * HDd;
        float x1 = ptr[d], x2 = ptr[d + HALF];
        float c1 = cosb[s * HDd + d], s1 = sinb[s * HDd + d];
        float c2 = cosb[s * HDd + d + HALF], s2 = sinb[s * HDd + d + HALF];
        ptr[d]        = x1 * c1 - x2 * s1;
        ptr[d + HALF] = x2 * c2 + x1 * s2;
    }
}

__global__ void k_attn(const float* __restrict__ qkv, float* __restrict__ aout) {
    const int q = blockIdx.x, h = blockIdx.y, b = blockIdx.z;
    const int tid = threadIdx.x;
    __shared__ float p[Ss];
    __shared__ float qv[HDd];
    __shared__ float rmax[4], rsum[4];
    const size_t base = (size_t)b * Ss * QKVW;
    const float* qrow = qkv + base + (size_t)q * QKVW + h * HDd;
    if (tid < HDd) qv[tid] = qrow[tid];
    __syncthreads();
    const int nk = q + 1;
    const float scale = 0.13608276348795434f;
    float lmax = -3.0e38f;
    for (int k = tid; k < nk; k += 256) {
        const float* krow = qkv + base + (size_t)k * QKVW + Dm + h * HDd;
        float acc = 0.f;
        #pragma unroll
        for (int d = 0; d < HDd; ++d) acc += qv[d] * krow[d];
        acc *= scale;
        p[k] = acc;
        lmax = fmaxf(lmax, acc);
    }
    for (int o = 32; o; o >>= 1) lmax = fmaxf(lmax, __shfl_down(lmax, o, 64));
    if ((tid & 63) == 0) rmax[tid >> 6] = lmax;
    __syncthreads();
    const float m = fmaxf(fmaxf(rmax[0], rmax[1]), fmaxf(rmax[2], rmax[3]));
    float lsum = 0.f;
    for (int k = tid; k < nk; k += 256) {
        float e = expf(p[k] - m);
        p[k] = e;
        lsum += e;
    }
    for (int o = 32; o; o >>= 1) lsum += __shfl_down(lsum, o, 64);
    if ((tid & 63) == 0) rsum[tid >> 6] = lsum;
    __syncthreads();
    const float inv = 1.f / (rsum[0] + rsum[1] + rsum[2] + rsum[3]);
    for (int d = tid; d < HDd; d += 256) {
        const float* vcol = qkv + base + 2 * Dm + h * HDd + d;
        float acc = 0.f;
        for (int k = 0; k < nk; ++k) acc += p[k] * vcol[(size_t)k * QKVW];
        aout[(size_t)(b * Ss + q) * Dm + h * HDd + d] = acc * inv;
    }
}

// =====================================================================
extern "C" void kernel_launch(void* const* d_in, const int* in_sizes, int n_in,
                              void* d_out, int out_size, void* d_ws, size_t ws_size,
                              hipStream_t stream) {
    const int*   ids    = (const int*)d_in[0];
    const float* emb    = (const float*)d_in[1];
    const float* ln1_w  = (const float*)d_in[2];
    const float* qkv_w  = (const float*)d_in[3];
    const float* o_w    = (const float*)d_in[4];
    const float* ln2_w  = (const float*)d_in[5];
    const float* gate_w = (const float*)d_in[6];
    const float* up_w   = (const float*)d_in[7];
    const float* down_w = (const float*)d_in[8];
    const float* norm_w = (const float*)d_in[9];
    const float* lm_w   = (const float*)d_in[10];
    float* out = (float*)d_out;

    char* base = (char*)d_ws;
    size_t off = 0;
    auto carve = [&](size_t bytes) -> char* {
        char* p = base + off;
        off += (bytes + 255) & ~(size_t)255;
        return p;
    };

    // fp32 buffers
    float* x    = (float*)carve((size_t)Tt * Dm * 4);
    float* qkv  = (float*)carve((size_t)Tt * QKVW * 4);
    float* gu   = (float*)carve((size_t)Tt * GUN * 4);
    float* cosb = (float*)carve((size_t)Ss * HDd * 4);
    float* sinb = (float*)carve((size_t)Ss * HDd * 4);
    // bf16 buffers
    unsigned short* h    = (unsigned short*)carve((size_t)Tt * KP * 2);
    unsigned short* aout = (unsigned short*)carve((size_t)Tt * KP * 2);
    unsigned short* act  = (unsigned short*)carve((size_t)Tt * FFf * 2);
    unsigned short* Qb   = (unsigned short*)carve((size_t)Bb * NHh * VTSZ * 2);
    unsigned short* Kb   = (unsigned short*)carve((size_t)Bb * NHh * VTSZ * 2);
    unsigned short* Vt   = (unsigned short*)carve((size_t)Bb * NHh * VTSZ * 2);
    unsigned short* qkvw = (unsigned short*)carve((size_t)NLAY * 768 * KP * 2);
    unsigned short* ow   = (unsigned short*)carve((size_t)NLAY * 256 * KP * 2);
    unsigned short* guw  = (unsigned short*)carve((size_t)NLAY * 1792 * KP * 2);
    unsigned short* dww  = (unsigned short*)carve((size_t)NLAY * 256 * 864 * 2);
    unsigned short* lmw  = (unsigned short*)carve((size_t)Vv * KP * 2);
    size_t need = off;

    if (ws_size >= need) {
        // -------- bf16 MFMA path --------
        k_embed<<<Tt, 256, 0, stream>>>(ids, emb, x);
        k_rope_tables<<<Ss, 64, 0, stream>>>(cosb, sinb);

        k_convw<<<512, 256, 0, stream>>>(qkv_w, qkvw, NLAY, QKVW, Dm, 768, KP, 768L * KP, 0);
        k_convw<<<256, 256, 0, stream>>>(o_w,   ow,   NLAY, Dm,   Dm, 256, KP, 256L * KP, 0);
        k_convw<<<512, 256, 0, stream>>>(gate_w, guw, NLAY, FFf,  Dm, 864, KP, 1792L * KP, 0);
        k_convw<<<512, 256, 0, stream>>>(up_w,   guw, NLAY, FFf,  Dm, 928, KP, 1792L * KP, 864L * KP);
        k_convw<<<512, 256, 0, stream>>>(down_w, dww, NLAY, Dm,  FFf, 256, 864, 256L * 864, 0);
        k_convw<<<1024, 256, 0, stream>>>(lm_w,  lmw, 1,    Vv,   Dm, Vv,  KP, (long)Vv * KP, 0);

        for (int l = 0; l < NLAY; ++l) {
            k_rmsnorm_bf<<<Tt, 64, 0, stream>>>(x, ln1_w + (size_t)l * Dm, h);
            k_mfma_gemm<<<dim3(16, 6), 256, 0, stream>>>(h, qkvw + (size_t)l * 768 * KP,
                                                         nullptr, qkv, QKVW, KP);
            k_prep_qk<<<Tt, 256, 0, stream>>>(qkv, cosb, sinb, Qb, Kb);
            k_prep_v<<<dim3(Ss / 64, NHh, Bb), 256, 0, stream>>>(qkv, Vt);
            k_attn_fa<<<dim3(Ss / 32, NHh, Bb), 128, 0, stream>>>(Qb, Kb, Vt, aout);
            k_mfma_gemm<<<dim3(16, 2), 256, 0, stream>>>(aout, ow + (size_t)l * 256 * KP,
                                                         x, x, Dm, KP);
            k_rmsnorm_bf<<<Tt, 64, 0, stream>>>(x, ln2_w + (size_t)l * Dm, h);
            k_mfma_gemm<<<dim3(16, 14), 256, 0, stream>>>(h, guw + (size_t)l * 1792 * KP,
                                                          nullptr, gu, GUN, KP);
            k_silu<<<(Tt * FFf + 255) / 256, 256, 0, stream>>>(gu, act);
            k_mfma_gemm<<<dim3(16, 2), 256, 0, stream>>>(act, dww + (size_t)l * 256 * 864,
                                                         x, x, Dm, 864);
        }
        k_rmsnorm_bf<<<Tt, 64, 0, stream>>>(x, norm_w, h);
        k_mfma_gemm<<<dim3(16, 250), 256, 0, stream>>>(h, lmw, nullptr, out, Vv, KP);
    } else {
        // -------- legacy fp32 fallback --------
        float* ws = (float*)d_ws;
        size_t o2 = 0;
        float* x2    = ws + o2; o2 += (size_t)Tt * Dm;
        float* h2    = ws + o2; o2 += (size_t)Tt * Dm;
        float* qkv2  = ws + o2; o2 += (size_t)Tt * QKVW;
        float* aout2 = ws + o2; o2 += (size_t)Tt * Dm;
        float* act2  = ws + o2; o2 += (size_t)Tt * FFf;
        float* cosb2 = ws + o2; o2 += (size_t)Ss * HDd;
        float* sinb2 = ws + o2; o2 += (size_t)Ss * HDd;

        k_embed<<<Tt, 256, 0, stream>>>(ids, emb, x2);
        k_rope_tables<<<Ss, 64, 0, stream>>>(cosb2, sinb2);
        dim3 blk(TS, TS);
        for (int l = 0; l < NLAY; ++l) {
            k_rmsnorm<<<Tt, 64, 0, stream>>>(x2, ln1_w + (size_t)l * Dm, h2);
            k_gemm<<<dim3((QKVW + TS - 1) / TS, (Tt + TS - 1) / TS), blk, 0, stream>>>(
                h2, qkv_w + (size_t)l * QKVW * Dm, nullptr, qkv2, Tt, QKVW, Dm);
            k_rope<<<Tt, 256, 0, stream>>>(qkv2, cosb2, sinb2);
            k_attn<<<dim3(Ss, NHh, Bb), 256, 0, stream>>>(qkv2, aout2);
            k_gemm<<<dim3((Dm + TS - 1) / TS, (Tt + TS - 1) / TS), blk, 0, stream>>>(
                aout2, o_w + (size_t)l * Dm * Dm, x2, x2, Tt, Dm, Dm);
            k_rmsnorm<<<Tt, 64, 0, stream>>>(x2, ln2_w + (size_t)l * Dm, h2);
            k_gateup<<<dim3((FFf + TS - 1) / TS, (Tt + TS - 1) / TS), blk, 0, stream>>>(
                h2, gate_w + (size_t)l * FFf * Dm, up_w + (size_t)l * FFf * Dm, act2, Tt, FFf, Dm);
            k_gemm<<<dim3((Dm + TS - 1) / TS, (Tt + TS - 1) / TS), blk, 0, stream>>>(
                act2, down_w + (size_t)l * Dm * FFf, x2, x2, Tt, Dm, FFf);
        }
        k_rmsnorm<<<Tt, 64, 0, stream>>>(x2, norm_w, h2);
        k_gemm<<<dim3((Vv + TS - 1) / TS, (Tt + TS - 1) / TS), blk, 0, stream>>>(
            h2, lm_w, nullptr, out, Tt, Vv, Dm);
    }
}

// Round 5
// 1712.676 us; speedup vs baseline: 4.1912x; 1.1079x over previous
//
#include <hip/hip_runtime.h>
#include <math.h>

#define Vv 32000
#define Dm 216
#define NLAY 11
#define NHh 4
#define HDd 54
#define FFf 864
#define Bb 2
#define Ss 1024
#define Tt (Bb*Ss)
#define EPSf 1e-5f
#define QKVW 648   // 3*Dm
#define KP 224     // K=216 padded to multiple of 32
#define HDP 64     // head dim padded
#define VTSZ (Ss*HDP)

typedef __attribute__((ext_vector_type(8))) short short8;
typedef __attribute__((ext_vector_type(8))) unsigned short ushort8;
typedef __attribute__((ext_vector_type(4))) float f32x4;

__device__ __forceinline__ unsigned short f2bf(float f) {
    unsigned int u = __float_as_uint(f);
    return (unsigned short)((u + 0x7fffu + ((u >> 16) & 1u)) >> 16);
}
__device__ __forceinline__ float bf2f(unsigned short u) {
    return __uint_as_float(((unsigned int)u) << 16);
}

// ---------------- embed gather ----------------
__global__ void k_embed(const int* __restrict__ ids, const float* __restrict__ emb,
                        float* __restrict__ x) {
    int t = blockIdx.x;
    int id = ids[t];
    for (int d = threadIdx.x; d < Dm; d += blockDim.x)
        x[(size_t)t * Dm + d] = emb[(size_t)id * Dm + d];
}

// ---------------- rope tables ----------------
__global__ void k_rope_tables(float* __restrict__ cosb, float* __restrict__ sinb) {
    int s = blockIdx.x;
    for (int d = threadIdx.x; d < HDd; d += blockDim.x) {
        int j = d % (HDd / 2);
        float inv = powf(10000.0f, -2.0f * (float)j / (float)HDd);
        float f = (float)s * inv;
        cosb[s * HDd + d] = cosf(f);
        sinb[s * HDd + d] = sinf(f);
    }
}

// ---------------- weight fp32 -> bf16 (padded, row-stride for interleave) --------
__global__ void k_convw(const float* __restrict__ src, unsigned short* __restrict__ dst,
                        int L, int N, int K, int Npad, int Kp, int rstride,
                        long dls, long doff) {
    size_t total = (size_t)L * Npad * Kp;
    for (size_t idx = (size_t)blockIdx.x * blockDim.x + threadIdx.x; idx < total;
         idx += (size_t)gridDim.x * blockDim.x) {
        int k = (int)(idx % Kp);
        size_t r = idx / Kp;
        int n = (int)(r % Npad);
        int l = (int)(r / Npad);
        float v = (n < N && k < K) ? src[((size_t)l * N + n) * K + k] : 0.f;
        dst[(size_t)l * dls + doff + (size_t)n * rstride + k] = f2bf(v);
    }
}

// ---------------- rmsnorm -> bf16 (K-padded with zeros); only used before LM head --
__global__ void k_rmsnorm_bf(const float* __restrict__ x, const float* __restrict__ w,
                             unsigned short* __restrict__ h) {
    int t = blockIdx.x;
    const float* xr = x + (size_t)t * Dm;
    float ss = 0.f;
    for (int d = threadIdx.x; d < Dm; d += 64) { float v = xr[d]; ss += v * v; }
    for (int o = 32; o; o >>= 1) ss += __shfl_down(ss, o, 64);
    float r = __shfl(ss, 0, 64);
    r = rsqrtf(r / (float)Dm + EPSf);
    for (int d = threadIdx.x; d < KP; d += 64)
        h[(size_t)t * KP + d] = (d < Dm) ? f2bf(xr[d] * r * w[d]) : (unsigned short)0;
}

// ---------------- fused MFMA GEMM ----------------
// OUTM: 0 = fp32 (+optional residual), 1 = bf16, 2 = bf16 silu(gate)*up (interleaved W)
// NORMA: A is fp32 [2048][216] rmsnorm'd on the fly with lnw; else A bf16 [2048][Kp].
// 128x128 tile, BK=32, 4 waves, double-buffered LDS in fragment order.
template<int OUTM, bool NORMA>
__global__ __launch_bounds__(256, 2) void k_gemm_f(
    const void* __restrict__ Av, const unsigned short* __restrict__ W,
    const float* __restrict__ res, void* __restrict__ outv,
    const float* __restrict__ lnw, int N, int Kp)
{
    __shared__ __align__(16) unsigned short lds[2][2][4096];
    __shared__ float rsl[128];
    __shared__ float lnl[224];
    const int tid = threadIdx.x;
    const int m0 = blockIdx.x * 128;
    const int n0 = blockIdx.y * 128;
    const int wid = tid >> 6, lane = tid & 63;
    const int wr = wid >> 1, wc = wid & 1;
    const int nsteps = Kp >> 5;

    if constexpr (NORMA) {
        const float* Af = (const float*)Av;
        if (tid < 224) lnl[tid] = (tid < 216) ? lnw[tid] : 0.f;
        int row = tid >> 1, half = tid & 1;
        const float* xr = Af + (size_t)(m0 + row) * 216 + half * 108;
        float ss = 0.f;
        #pragma unroll
        for (int q = 0; q < 27; ++q) {
            float4 v = *(const float4*)(xr + q * 4);
            ss += v.x * v.x + v.y * v.y + v.z * v.z + v.w * v.w;
        }
        ss += __shfl_xor(ss, 1, 64);
        if (half == 0) rsl[row] = rsqrtf(ss / 216.f + EPSf);
        __syncthreads();
    }

    const int i0 = tid, i1 = tid + 256;
    const int rA0 = i0 >> 2, cA0 = i0 & 3;
    const int rA1 = i1 >> 2, cA1 = i1 & 3;
    const int lo0 = (rA0 >> 4) * 512 + (((cA0 << 4) | (rA0 & 15)) << 3);
    const int lo1 = (rA1 >> 4) * 512 + (((cA1 << 4) | (rA1 & 15)) << 3);

    auto loadA = [&](int row, int base) -> ushort8 {
        ushort8 o;
        if constexpr (NORMA) {
            if (base < 216) {
                const float* p = (const float*)Av + (size_t)(m0 + row) * 216 + base;
                float r = rsl[row];
                float4 v0 = *(const float4*)p;
                float4 v1 = *(const float4*)(p + 4);
                o[0] = f2bf(v0.x * r * lnl[base + 0]);
                o[1] = f2bf(v0.y * r * lnl[base + 1]);
                o[2] = f2bf(v0.z * r * lnl[base + 2]);
                o[3] = f2bf(v0.w * r * lnl[base + 3]);
                o[4] = f2bf(v1.x * r * lnl[base + 4]);
                o[5] = f2bf(v1.y * r * lnl[base + 5]);
                o[6] = f2bf(v1.z * r * lnl[base + 6]);
                o[7] = f2bf(v1.w * r * lnl[base + 7]);
            } else {
                #pragma unroll
                for (int e = 0; e < 8; ++e) o[e] = 0;
            }
        } else {
            o = *(const ushort8*)((const unsigned short*)Av + (size_t)(m0 + row) * Kp + base);
        }
        return o;
    };

    ushort8 ra0, ra1, rb0, rb1;
    ra0 = loadA(rA0, cA0 * 8);
    ra1 = loadA(rA1, cA1 * 8);
    rb0 = *(const ushort8*)(W + (size_t)(n0 + rA0) * Kp + cA0 * 8);
    rb1 = *(const ushort8*)(W + (size_t)(n0 + rA1) * Kp + cA1 * 8);
    *(ushort8*)&lds[0][0][lo0] = ra0;
    *(ushort8*)&lds[0][0][lo1] = ra1;
    *(ushort8*)&lds[0][1][lo0] = rb0;
    *(ushort8*)&lds[0][1][lo1] = rb1;
    __syncthreads();

    f32x4 acc[4][4] = {};

    int cur = 0;
    for (int step = 0; step < nsteps; ++step) {
        const bool more = (step + 1) < nsteps;
        if (more) {
            const int k0 = (step + 1) << 5;
            ra0 = loadA(rA0, k0 + cA0 * 8);
            ra1 = loadA(rA1, k0 + cA1 * 8);
            rb0 = *(const ushort8*)(W + (size_t)(n0 + rA0) * Kp + k0 + cA0 * 8);
            rb1 = *(const ushort8*)(W + (size_t)(n0 + rA1) * Kp + k0 + cA1 * 8);
        }
        short8 af[4], bf[4];
        #pragma unroll
        for (int f = 0; f < 4; ++f) {
            af[f] = *(const short8*)&lds[cur][0][(wr * 4 + f) * 512 + lane * 8];
            bf[f] = *(const short8*)&lds[cur][1][(wc * 4 + f) * 512 + lane * 8];
        }
        #pragma unroll
        for (int fm = 0; fm < 4; ++fm)
            #pragma unroll
            for (int fn = 0; fn < 4; ++fn)
                acc[fm][fn] = __builtin_amdgcn_mfma_f32_16x16x32_bf16(af[fm], bf[fn], acc[fm][fn], 0, 0, 0);
        if (more) {
            const int nxt = cur ^ 1;
            *(ushort8*)&lds[nxt][0][lo0] = ra0;
            *(ushort8*)&lds[nxt][0][lo1] = ra1;
            *(ushort8*)&lds[nxt][1][lo0] = rb0;
            *(ushort8*)&lds[nxt][1][lo1] = rb1;
            __syncthreads();
            cur = nxt;
        }
    }

    const int lc16 = lane & 15;
    #pragma unroll
    for (int fm = 0; fm < 4; ++fm) {
        const int mrow = m0 + wr * 64 + fm * 16 + (lane >> 4) * 4;
        #pragma unroll
        for (int fn = 0; fn < 4; ++fn) {
            const int ncol = n0 + wc * 64 + fn * 16 + lc16;
            #pragma unroll
            for (int i = 0; i < 4; ++i) {
                float v = acc[fm][fn][i];
                if constexpr (OUTM == 2) {
                    float p = __shfl_xor(v, 1, 64);
                    if ((lc16 & 1) == 0 && ncol < N) {
                        float y = v / (1.f + __expf(-v)) * p;
                        ((unsigned short*)outv)[(size_t)(mrow + i) * (N >> 1) + (ncol >> 1)] = f2bf(y);
                    }
                } else if constexpr (OUTM == 1) {
                    if (ncol < N)
                        ((unsigned short*)outv)[(size_t)(mrow + i) * N + ncol] = f2bf(v);
                } else {
                    if (ncol < N) {
                        const size_t oi = (size_t)(mrow + i) * N + ncol;
                        if (res) v += res[oi];
                        ((float*)outv)[oi] = v;
                    }
                }
            }
        }
    }
}

// ---------------- prep: K-rope + V-transpose (reads bf16 qkv) ----------------
// grid (Ss/64, NHh, Bb), 256 threads. Kb: [bh][S][64], Vt: [bh][64][S].
__global__ void k_prep(const unsigned short* __restrict__ qkvb,
                       const float* __restrict__ cosb, const float* __restrict__ sinb,
                       unsigned short* __restrict__ Kb, unsigned short* __restrict__ Vt) {
    __shared__ __align__(16) unsigned short lv[64 * 72];
    const int s0 = blockIdx.x * 64;
    const int h = blockIdx.y, b = blockIdx.z;
    const int bh = b * NHh + h;
    const int tid = threadIdx.x;
    // K rope
    for (int idx = tid; idx < 64 * 27; idx += 256) {
        int r = idx / 27, j = idx % 27;
        int s = s0 + r;
        const unsigned short* kr = qkvb + (size_t)(b * Ss + s) * QKVW + Dm + h * HDd;
        float x1 = bf2f(kr[j]), x2 = bf2f(kr[j + 27]);
        float c = cosb[s * HDd + j], sn = sinb[s * HDd + j];
        unsigned short* kd = Kb + ((size_t)bh * Ss + s) * HDP;
        kd[j] = f2bf(x1 * c - x2 * sn);
        kd[j + 27] = f2bf(x2 * c + x1 * sn);
    }
    for (int idx = tid; idx < 64 * 10; idx += 256) {
        int r = idx / 10, d = 54 + idx % 10;
        Kb[((size_t)bh * Ss + s0 + r) * HDP + d] = 0;
    }
    // V transpose into LDS
    for (int idx = tid; idx < 64 * 8; idx += 256) {
        int sr = idx >> 3, dc = idx & 7;
        if (dc < 7) {
            ushort8 v = *(const ushort8*)(qkvb + (size_t)(b * Ss + s0 + sr) * QKVW + 2 * Dm + h * HDd + dc * 8);
            #pragma unroll
            for (int e = 0; e < 8; ++e) {
                int d = dc * 8 + e;
                if (d < HDd) lv[d * 72 + sr] = v[e];
            }
        } else {
            #pragma unroll
            for (int e = 0; e < 8; ++e) lv[(56 + e) * 72 + sr] = 0;
        }
    }
    for (int idx = tid; idx < 128; idx += 256) {
        int sr = idx & 63, d = 54 + (idx >> 6);
        lv[d * 72 + sr] = 0;
    }
    __syncthreads();
    unsigned short* dstb = Vt + (size_t)bh * VTSZ;
    for (int c = tid; c < 512; c += 256) {
        int d = c >> 3, sc = c & 7;
        *(ushort8*)(dstb + (size_t)d * Ss + s0 + sc * 8) = *(const ushort8*)&lv[d * 72 + sc * 8];
    }
}

// ---------------- MFMA flash attention (Q roped in-kernel from bf16 qkv) --------
__global__ __launch_bounds__(128) void k_attn_fa(
    const unsigned short* __restrict__ qkvb, const unsigned short* __restrict__ Kb,
    const unsigned short* __restrict__ Vt,
    const float* __restrict__ cosb, const float* __restrict__ sinb,
    unsigned short* __restrict__ aout)
{
    __shared__ __align__(16) unsigned short Kl[4096];
    __shared__ __align__(16) unsigned short Vl[4096];
    __shared__ __align__(16) unsigned short Pl[2048];
    __shared__ __align__(16) unsigned short Ql[2048];
    const int tid = threadIdx.x;
    const int qb = blockIdx.x, h = blockIdx.y, b = blockIdx.z;
    const int bh = b * NHh + h;
    const int q0 = qb * 32;
    const int w = tid >> 6, lane = tid & 63;
    const int q0w = q0 + w * 16;
    const int lc = lane & 15, lg = lane >> 4;
    const float scale = 0.13608276348795434f; // 54^-0.5

    if (h == 0) { // zero pad cols 216..223 of aout for this block's rows
        for (int idx = tid; idx < 32 * 8; idx += 128) {
            int r = idx >> 3, cpad = idx & 7;
            aout[(size_t)(b * Ss + q0 + r) * KP + Dm + cpad] = 0;
        }
    }

    // stage Q (roped, scaled) into fragment-order LDS
    for (int idx = tid; idx < 32 * 27; idx += 128) {
        int r = idx / 27, j = idx % 27;
        int s = q0 + r;
        const unsigned short* qr = qkvb + (size_t)(b * Ss + s) * QKVW + h * HDd;
        float q1 = bf2f(qr[j]), q2 = bf2f(qr[j + 27]);
        float c = cosb[s * HDd + j], sn = sinb[s * HDd + j];
        float o1 = (q1 * c - q2 * sn) * scale;
        float o2 = (q2 * c + q1 * sn) * scale;
        int st = r >> 4, rr = r & 15;
        Ql[st * 1024 + ((j >> 3) * 16 + rr) * 8 + (j & 7)] = f2bf(o1);
        int j2 = j + 27;
        Ql[st * 1024 + ((j2 >> 3) * 16 + rr) * 8 + (j2 & 7)] = f2bf(o2);
    }
    for (int idx = tid; idx < 32 * 10; idx += 128) {
        int r = idx / 10, d = 54 + idx % 10;
        Ql[(r >> 4) * 1024 + ((d >> 3) * 16 + (r & 15)) * 8 + (d & 7)] = 0;
    }
    __syncthreads();

    short8 qa[2];
    #pragma unroll
    for (int half = 0; half < 2; ++half)
        qa[half] = *(const short8*)&Ql[w * 1024 + ((half * 4 + lg) * 16 + lc) * 8];

    const unsigned short* Kpp = Kb + (size_t)bh * VTSZ;
    const unsigned short* Vp = Vt + (size_t)bh * VTSZ;

    f32x4 o4[4] = {};
    float mreg[4] = {-3e38f, -3e38f, -3e38f, -3e38f};
    float lreg[4] = {0.f, 0.f, 0.f, 0.f};

    const int nt = (q0 + 31) / 64 + 1;
    for (int t = 0; t < nt; ++t) {
        const int kv0 = t * 64;
        __syncthreads();
        for (int c = tid; c < 1024; c += 128) {
            if (c < 512) {
                int sub = c >> 6;
                int dhalf = sub >> 2, kgrp = sub & 3;
                int dchunk = (c >> 4) & 3, krow = c & 15;
                *(ushort8*)&Kl[sub * 512 + (c & 63) * 8] =
                    *(const ushort8*)(Kpp + (size_t)(kv0 + kgrp * 16 + krow) * HDP + dhalf * 32 + dchunk * 8);
            } else {
                int c2 = c - 512;
                int sub2 = c2 >> 6;
                int khalf = sub2 >> 2, dgrp = sub2 & 3;
                int kchunk = (c2 >> 4) & 3, drow = c2 & 15;
                *(ushort8*)&Vl[sub2 * 512 + (c2 & 63) * 8] =
                    *(const ushort8*)(Vp + (size_t)(dgrp * 16 + drow) * Ss + kv0 + khalf * 32 + kchunk * 8);
            }
        }
        __syncthreads();

        // QK^T: S[16q][64k]
        f32x4 s4[4] = {};
        #pragma unroll
        for (int half = 0; half < 2; ++half) {
            #pragma unroll
            for (int fn = 0; fn < 4; ++fn) {
                short8 kf = *(const short8*)&Kl[(half * 4 + fn) * 512 + lane * 8];
                s4[fn] = __builtin_amdgcn_mfma_f32_16x16x32_bf16(qa[half], kf, s4[fn], 0, 0, 0);
            }
        }
        // causal mask: needed whenever tile's max k exceeds wave's LOWEST q-row
        if (kv0 + 63 > q0w) {
            #pragma unroll
            for (int fn = 0; fn < 4; ++fn) {
                int kg = kv0 + fn * 16 + lc;
                #pragma unroll
                for (int r = 0; r < 4; ++r) {
                    int qg = q0w + lg * 4 + r;
                    if (kg > qg) s4[fn][r] = -3e38f;
                }
            }
        }
        // online softmax (each q-row lives in a 16-lane group)
        #pragma unroll
        for (int r = 0; r < 4; ++r) {
            float rm = fmaxf(fmaxf(s4[0][r], s4[1][r]), fmaxf(s4[2][r], s4[3][r]));
            #pragma unroll
            for (int msk = 1; msk < 16; msk <<= 1)
                rm = fmaxf(rm, __shfl_xor(rm, msk, 64));
            float mn = fmaxf(mreg[r], rm);
            float esc = __expf(mreg[r] - mn);
            mreg[r] = mn;
            float p0 = __expf(s4[0][r] - mn);
            float p1 = __expf(s4[1][r] - mn);
            float p2 = __expf(s4[2][r] - mn);
            float p3 = __expf(s4[3][r] - mn);
            float rs = p0 + p1 + p2 + p3;
            #pragma unroll
            for (int msk = 1; msk < 16; msk <<= 1)
                rs += __shfl_xor(rs, msk, 64);
            lreg[r] = lreg[r] * esc + rs;
            #pragma unroll
            for (int db = 0; db < 4; ++db) o4[db][r] *= esc;
            int q = lg * 4 + r;
            int kc = lc >> 3, ko = lc & 7;
            Pl[w * 1024 + ((0 * 2 + kc) * 16 + q) * 8 + ko] = f2bf(p0);
            Pl[w * 1024 + ((1 * 2 + kc) * 16 + q) * 8 + ko] = f2bf(p1);
            Pl[w * 1024 + ((2 * 2 + kc) * 16 + q) * 8 + ko] = f2bf(p2);
            Pl[w * 1024 + ((3 * 2 + kc) * 16 + q) * 8 + ko] = f2bf(p3);
        }
        // PV: O[16q][64d] += P[16q][64k] * V[64k][64d]
        short8 pa0 = *(const short8*)&Pl[w * 1024 + ((0 + lg) * 16 + lc) * 8];
        short8 pa1 = *(const short8*)&Pl[w * 1024 + ((4 + lg) * 16 + lc) * 8];
        #pragma unroll
        for (int db = 0; db < 4; ++db) {
            short8 vf0 = *(const short8*)&Vl[(0 + db) * 512 + lane * 8];
            o4[db] = __builtin_amdgcn_mfma_f32_16x16x32_bf16(pa0, vf0, o4[db], 0, 0, 0);
            short8 vf1 = *(const short8*)&Vl[(4 + db) * 512 + lane * 8];
            o4[db] = __builtin_amdgcn_mfma_f32_16x16x32_bf16(pa1, vf1, o4[db], 0, 0, 0);
        }
    }

    #pragma unroll
    for (int r = 0; r < 4; ++r) {
        float inv = 1.f / lreg[r];
        int row = b * Ss + q0w + lg * 4 + r;
        #pragma unroll
        for (int db = 0; db < 4; ++db) {
            int col = db * 16 + lc;
            if (col < HDd)
                aout[(size_t)row * KP + h * HDd + col] = f2bf(o4[db][r] * inv);
        }
    }
}

// ================= legacy fp32 fallback kernels =================
__global__ void k_rmsnorm(const float* __restrict__ x, const float* __restrict__ w,
                          float* __restrict__ h) {
    int t = blockIdx.x;
    const float* xr = x + (size_t)t * Dm;
    float ss = 0.f;
    for (int d = threadIdx.x; d < Dm; d += 64) { float v = xr[d]; ss += v * v; }
    for (int o = 32; o; o >>= 1) ss += __shfl_down(ss, o, 64);
    float r = __shfl(ss, 0, 64);
    r = rsqrtf(r / (float)Dm + EPSf);
    for (int d = threadIdx.x; d < Dm; d += 64)
        h[(size_t)t * Dm + d] = xr[d] * r * w[d];
}

#define TS 16
__global__ void k_gemm(const float* __restrict__ A, const float* __restrict__ W,
                       const float* __restrict__ res, float* __restrict__ out,
                       int M, int N, int K) {
    __shared__ float As[TS][TS + 1];
    __shared__ float Wsm[TS][TS + 1];
    const int tx = threadIdx.x, ty = threadIdx.y;
    const int m = blockIdx.y * TS + ty;
    const int n = blockIdx.x * TS + tx;
    float acc = 0.f;
    for (int k0 = 0; k0 < K; k0 += TS) {
        int ka = k0 + tx;
        As[ty][tx] = (m < M && ka < K) ? A[(size_t)m * K + ka] : 0.f;
        int nw = blockIdx.x * TS + ty;
        Wsm[ty][tx] = (nw < N && ka < K) ? W[(size_t)nw * K + ka] : 0.f;
        __syncthreads();
        #pragma unroll
        for (int kk = 0; kk < TS; ++kk) acc += As[ty][kk] * Wsm[tx][kk];
        __syncthreads();
    }
    if (m < M && n < N) {
        float r = res ? res[(size_t)m * N + n] : 0.f;
        out[(size_t)m * N + n] = r + acc;
    }
}

__global__ void k_gateup(const float* __restrict__ A, const float* __restrict__ Wg,
                         const float* __restrict__ Wu, float* __restrict__ act,
                         int M, int N, int K) {
    __shared__ float As[TS][TS + 1];
    __shared__ float Gs[TS][TS + 1];
    __shared__ float Us[TS][TS + 1];
    const int tx = threadIdx.x, ty = threadIdx.y;
    const int m = blockIdx.y * TS + ty;
    const int n = blockIdx.x * TS + tx;
    float ag = 0.f, au = 0.f;
    for (int k0 = 0; k0 < K; k0 += TS) {
        int ka = k0 + tx;
        As[ty][tx] = (m < M && ka < K) ? A[(size_t)m * K + ka] : 0.f;
        int nw = blockIdx.x * TS + ty;
        Gs[ty][tx] = (nw < N && ka < K) ? Wg[(size_t)nw * K + ka] : 0.f;
        Us[ty][tx] = (nw < N && ka < K) ? Wu[(size_t)nw * K + ka] : 0.f;
        __syncthreads();
        #pragma unroll
        for (int kk = 0; kk < TS; ++kk) {
            ag += As[ty][kk] * Gs[tx][kk];
            au += As[ty][kk] * Us[tx][kk];
        }
        __syncthreads();
    }
    if (m < M && n < N) {
        float sg = ag / (1.f + expf(-ag));
        act[(size_t)m * N + n] = sg * au;
    }
}

__global__ void k_rope(float* __restrict__ qkv, const float* __restrict__ cosb,
                       const float* __restrict__ sinb) {
    const int t = blockIdx.x;
    const int s = t % Ss;
    float* base = qkv + (size_t)t * QKVW;
    const int HALF = HDd / 2;
    int i = threadIdx.x;
    if (i < 2 * NHh * HALF) {
        int which = i / (NHh * HALF);
        int rem = i % (NHh * HALF);
        int hh = rem / HALF;
        int d = rem % HALF;
        float* ptr = base + which * Dm + hh * HDd;
        float x1 = ptr[d], x2 = ptr[d + HALF];
        float c1 = cosb[s * HDd + d], s1 = sinb[s * HDd + d];
        float c2 = cosb[s * HDd + d + HALF], s2 = sinb[s * HDd + d + HALF];
        ptr[d]        = x1 * c1 - x2 * s1;
        ptr[d + HALF] = x2 * c2 + x1 * s2;
    }
}

__global__ void k_attn(const float* __restrict__ qkv, float* __restrict__ aout) {
    const int q = blockIdx.x, h = blockIdx.y, b = blockIdx.z;
    const int tid = threadIdx.x;
    __shared__ float p[Ss];
    __shared__ float qv[HDd];
    __shared__ float rmax[4], rsum[4];
    const size_t base = (size_t)b * Ss * QKVW;
    const float* qrow = qkv + base + (size_t)q * QKVW + h * HDd;
    if (tid < HDd) qv[tid] = qrow[tid];
    __syncthreads();
    const int nk = q + 1;
    const float scale = 0.13608276348795434f;
    float lmax = -3.0e38f;
    for (int k = tid; k < nk; k += 256) {
        const float* krow = qkv + base + (size_t)k * QKVW + Dm + h * HDd;
        float acc = 0.f;
        #pragma unroll
        for (int d = 0; d < HDd; ++d) acc += qv[d] * krow[d];
        acc *= scale;
        p[k] = acc;
        lmax = fmaxf(lmax, acc);
    }
    for (int o = 32; o; o >>= 1) lmax = fmaxf(lmax, __shfl_down(lmax, o, 64));
    if ((tid & 63) == 0) rmax[tid >> 6] = lmax;
    __syncthreads();
    const float m = fmaxf(fmaxf(rmax[0], rmax[1]), fmaxf(rmax[2], rmax[3]));
    float lsum = 0.f;
    for (int k = tid; k < nk; k += 256) {
        float e = expf(p[k] - m);
        p[k] = e;
        lsum += e;
    }
    for (int o = 32; o; o >>= 1) lsum += __shfl_down(lsum, o, 64);
    if ((tid & 63) == 0) rsum[tid >> 6] = lsum;
    __syncthreads();
    const float inv = 1.f / (rsum[0] + rsum[1] + rsum[2] + rsum[3]);
    for (int d = tid; d < HDd; d += 256) {
        const float* vcol = qkv + base + 2 * Dm + h * HDd + d;
        float acc = 0.f;
        for (int k = 0; k < nk; ++k) acc += p[k] * vcol[(size_t)k * QKVW];
        aout[(size_t)(b * Ss + q) * Dm + h * HDd + d] = acc * inv;
    }
}

// =====================================================================
extern "C" void kernel_launch(void* const* d_in, const int* in_sizes, int n_in,
                              void* d_out, int out_size, void* d_ws, size_t ws_size,
                              hipStream_t stream) {
    const int*   ids    = (const int*)d_in[0];
    const float* emb    = (const float*)d_in[1];
    const float* ln1_w  = (const float*)d_in[2];
    const float* qkv_w  = (const float*)d_in[3];
    const float* o_w    = (const float*)d_in[4];
    const float* ln2_w  = (const float*)d_in[5];
    const float* gate_w = (const float*)d_in[6];
    const float* up_w   = (const float*)d_in[7];
    const float* down_w = (const float*)d_in[8];
    const float* norm_w = (const float*)d_in[9];
    const float* lm_w   = (const float*)d_in[10];
    float* out = (float*)d_out;

    char* base = (char*)d_ws;
    size_t off = 0;
    auto carve = [&](size_t bytes) -> char* {
        char* p = base + off;
        off += (bytes + 255) & ~(size_t)255;
        return p;
    };

    // fp32 buffers
    float* x    = (float*)carve((size_t)Tt * Dm * 4);
    float* cosb = (float*)carve((size_t)Ss * HDd * 4);
    float* sinb = (float*)carve((size_t)Ss * HDd * 4);
    // bf16 buffers
    unsigned short* qkvb = (unsigned short*)carve(((size_t)Tt * QKVW + 16) * 2);
    unsigned short* Kb   = (unsigned short*)carve((size_t)Bb * NHh * VTSZ * 2);
    unsigned short* Vt   = (unsigned short*)carve((size_t)Bb * NHh * VTSZ * 2);
    unsigned short* aout = (unsigned short*)carve((size_t)Tt * KP * 2);
    unsigned short* act  = (unsigned short*)carve((size_t)Tt * FFf * 2);
    unsigned short* h    = (unsigned short*)carve((size_t)Tt * KP * 2);
    unsigned short* qkvw = (unsigned short*)carve((size_t)NLAY * 768 * KP * 2);
    unsigned short* ow   = (unsigned short*)carve((size_t)NLAY * 256 * KP * 2);
    unsigned short* guw  = (unsigned short*)carve((size_t)NLAY * 1792 * KP * 2);
    unsigned short* dww  = (unsigned short*)carve((size_t)NLAY * 256 * 864 * 2);
    unsigned short* lmw  = (unsigned short*)carve((size_t)Vv * KP * 2);
    size_t need = off;

    if (ws_size >= need) {
        // -------- fused bf16 MFMA path --------
        k_embed<<<Tt, 256, 0, stream>>>(ids, emb, x);
        k_rope_tables<<<Ss, 64, 0, stream>>>(cosb, sinb);

        k_convw<<<512, 256, 0, stream>>>(qkv_w, qkvw, NLAY, QKVW, Dm, 768, KP, KP, 768L * KP, 0);
        k_convw<<<256, 256, 0, stream>>>(o_w,   ow,   NLAY, Dm,   Dm, 256, KP, KP, 256L * KP, 0);
        k_convw<<<512, 256, 0, stream>>>(gate_w, guw, NLAY, FFf,  Dm, 896, KP, 2 * KP, 1792L * KP, 0);
        k_convw<<<512, 256, 0, stream>>>(up_w,   guw, NLAY, FFf,  Dm, 896, KP, 2 * KP, 1792L * KP, KP);
        k_convw<<<512, 256, 0, stream>>>(down_w, dww, NLAY, Dm,  FFf, 256, 864, 864, 256L * 864, 0);
        k_convw<<<1024, 256, 0, stream>>>(lm_w,  lmw, 1,    Vv,   Dm, Vv,  KP, KP, (long)Vv * KP, 0);

        for (int l = 0; l < NLAY; ++l) {
            k_gemm_f<1, true><<<dim3(16, 6), 256, 0, stream>>>(
                x, qkvw + (size_t)l * 768 * KP, nullptr, qkvb,
                ln1_w + (size_t)l * Dm, QKVW, KP);
            k_prep<<<dim3(Ss / 64, NHh, Bb), 256, 0, stream>>>(qkvb, cosb, sinb, Kb, Vt);
            k_attn_fa<<<dim3(Ss / 32, NHh, Bb), 128, 0, stream>>>(qkvb, Kb, Vt, cosb, sinb, aout);
            k_gemm_f<0, false><<<dim3(16, 2), 256, 0, stream>>>(
                aout, ow + (size_t)l * 256 * KP, x, x, nullptr, Dm, KP);
            k_gemm_f<2, true><<<dim3(16, 14), 256, 0, stream>>>(
                x, guw + (size_t)l * 1792 * KP, nullptr, act,
                ln2_w + (size_t)l * Dm, 2 * FFf, KP);
            k_gemm_f<0, false><<<dim3(16, 2), 256, 0, stream>>>(
                act, dww + (size_t)l * 256 * 864, x, x, nullptr, Dm, 864);
        }
        k_rmsnorm_bf<<<Tt, 64, 0, stream>>>(x, norm_w, h);
        k_gemm_f<0, false><<<dim3(16, 250), 256, 0, stream>>>(
            h, lmw, nullptr, out, nullptr, Vv, KP);
    } else {
        // -------- legacy fp32 fallback --------
        float* ws = (float*)d_ws;
        size_t o2 = 0;
        float* x2    = ws + o2; o2 += (size_t)Tt * Dm;
        float* h2    = ws + o2; o2 += (size_t)Tt * Dm;
        float* qkv2  = ws + o2; o2 += (size_t)Tt * QKVW;
        float* aout2 = ws + o2; o2 += (size_t)Tt * Dm;
        float* act2  = ws + o2; o2 += (size_t)Tt * FFf;
        float* cosb2 = ws + o2; o2 += (size_t)Ss * HDd;
        float* sinb2 = ws + o2; o2 += (size_t)Ss * HDd;

        k_embed<<<Tt, 256, 0, stream>>>(ids, emb, x2);
        k_rope_tables<<<Ss, 64, 0, stream>>>(cosb2, sinb2);
        dim3 blk(TS, TS);
        for (int l = 0; l < NLAY; ++l) {
            k_rmsnorm<<<Tt, 64, 0, stream>>>(x2, ln1_w + (size_t)l * Dm, h2);
            k_gemm<<<dim3((QKVW + TS - 1) / TS, (Tt + TS - 1) / TS), blk, 0, stream>>>(
                h2, qkv_w + (size_t)l * QKVW * Dm, nullptr, qkv2, Tt, QKVW, Dm);
            k_rope<<<Tt, 256, 0, stream>>>(qkv2, cosb2, sinb2);
            k_attn<<<dim3(Ss, NHh, Bb), 256, 0, stream>>>(qkv2, aout2);
            k_gemm<<<dim3((Dm + TS - 1) / TS, (Tt + TS - 1) / TS), blk, 0, stream>>>(
                aout2, o_w + (size_t)l * Dm * Dm, x2, x2, Tt, Dm, Dm);
            k_rmsnorm<<<Tt, 64, 0, stream>>>(x2, ln2_w + (size_t)l * Dm, h2);
            k_gateup<<<dim3((FFf + TS - 1) / TS, (Tt + TS - 1) / TS), blk, 0, stream>>>(
                h2, gate_w + (size_t)l * FFf * Dm, up_w + (size_t)l * FFf * Dm, act2, Tt, FFf, Dm);
            k_gemm<<<dim3((Dm + TS - 1) / TS, (Tt + TS - 1) / TS), blk, 0, stream>>>(
                act2, down_w + (size_t)l * Dm * FFf, x2, x2, Tt, Dm, FFf);
        }
        k_rmsnorm<<<Tt, 64, 0, stream>>>(x2, norm_w, h2);
        k_gemm<<<dim3((Vv + TS - 1) / TS, (Tt + TS - 1) / TS), blk, 0, stream>>>(
            h2, lm_w, nullptr, out, Tt, Vv, Dm);
    }
}

// Round 6
// 1406.054 us; speedup vs baseline: 5.1052x; 1.2181x over previous
//
#include <hip/hip_runtime.h>
#include <math.h>

#define Vv 32000
#define Dm 216
#define NLAY 11
#define NHh 4
#define HDd 54
#define FFf 864
#define Bb 2
#define Ss 1024
#define Tt (Bb*Ss)
#define EPSf 1e-5f
#define QKVW 648   // 3*Dm
#define KP 224     // K=216 padded to multiple of 32
#define HDP 64     // head dim padded
#define VTSZ (Ss*HDP)

typedef __attribute__((ext_vector_type(8))) short short8;
typedef __attribute__((ext_vector_type(8))) unsigned short ushort8;
typedef __attribute__((ext_vector_type(4))) float f32x4;

__device__ __forceinline__ unsigned short f2bf(float f) {
    unsigned int u = __float_as_uint(f);
    return (unsigned short)((u + 0x7fffu + ((u >> 16) & 1u)) >> 16);
}
__device__ __forceinline__ float bf2f(unsigned short u) {
    return __uint_as_float(((unsigned int)u) << 16);
}

// ---------------- zero-fill (pads of Qb/Kb/Vt/aout, once per call) ----------------
__global__ void k_zero(unsigned int* __restrict__ p, size_t n) {
    size_t i = (size_t)blockIdx.x * blockDim.x + threadIdx.x;
    size_t stride = (size_t)gridDim.x * blockDim.x;
    for (; i < n; i += stride) p[i] = 0;
}

// ---------------- embed gather ----------------
__global__ void k_embed(const int* __restrict__ ids, const float* __restrict__ emb,
                        float* __restrict__ x) {
    int t = blockIdx.x;
    int id = ids[t];
    for (int d = threadIdx.x; d < Dm; d += blockDim.x)
        x[(size_t)t * Dm + d] = emb[(size_t)id * Dm + d];
}

// ---------------- rope tables (27-wide: cos/sin same for j and j+27) ----------------
__global__ void k_rope_tables27(float* __restrict__ cost, float* __restrict__ sint) {
    int s = blockIdx.x;
    int j = threadIdx.x;
    if (j < 27) {
        float inv = powf(10000.0f, -2.0f * (float)j / 54.0f);
        float f = (float)s * inv;
        cost[s * 27 + j] = cosf(f);
        sint[s * 27 + j] = sinf(f);
    }
}

// ---------------- rope tables 54-wide (legacy fallback only) ----------------
__global__ void k_rope_tables(float* __restrict__ cosb, float* __restrict__ sinb) {
    int s = blockIdx.x;
    for (int d = threadIdx.x; d < HDd; d += blockDim.x) {
        int j = d % (HDd / 2);
        float inv = powf(10000.0f, -2.0f * (float)j / (float)HDd);
        float f = (float)s * inv;
        cosb[s * HDd + d] = cosf(f);
        sinb[s * HDd + d] = sinf(f);
    }
}

// ---------------- generic weight fp32 -> bf16 (padded, row-stride for interleave) --
__global__ void k_convw(const float* __restrict__ src, unsigned short* __restrict__ dst,
                        int L, int N, int K, int Npad, int Kp, int rstride,
                        long dls, long doff) {
    size_t total = (size_t)L * Npad * Kp;
    for (size_t idx = (size_t)blockIdx.x * blockDim.x + threadIdx.x; idx < total;
         idx += (size_t)gridDim.x * blockDim.x) {
        int k = (int)(idx % Kp);
        size_t r = idx / Kp;
        int n = (int)(r % Npad);
        int l = (int)(r / Npad);
        float v = (n < N && k < K) ? src[((size_t)l * N + n) * K + k] : 0.f;
        dst[(size_t)l * dls + doff + (size_t)n * rstride + k] = f2bf(v);
    }
}

// ---------------- qkv weight conv: rope-paired column order + q scale fold ----------
// dst rows nr: q [0,216) paired (head*54 + 2j -> src j, 2j+1 -> src j+27, * scale),
//              k [216,432) paired, v [432,648) natural, [648,768) zero.
__global__ void k_convqkv(const float* __restrict__ src, unsigned short* __restrict__ dst) {
    size_t total = (size_t)NLAY * 768 * KP;
    for (size_t idx = (size_t)blockIdx.x * blockDim.x + threadIdx.x; idx < total;
         idx += (size_t)gridDim.x * blockDim.x) {
        int kk = (int)(idx % KP);
        size_t r = idx / KP;
        int nr = (int)(r % 768);
        int l = (int)(r / 768);
        float v = 0.f;
        if (nr < 648 && kk < 216) {
            int srow;
            float sc = 1.f;
            if (nr < 432) {
                int which = nr >= 216;
                int cih = nr - which * 216;
                int head = cih / 54, dd = cih % 54;
                int j = dd >> 1, odd = dd & 1;
                srow = which * 216 + head * 54 + j + odd * 27;
                if (!which) sc = 0.13608276348795434f; // 54^-0.5 folded into q
            } else srow = nr;
            v = src[((size_t)l * QKVW + srow) * 216 + kk] * sc;
        }
        dst[idx] = f2bf(v);
    }
}

// ---------------- fused MFMA GEMM (128x128, BK=32, dbuf) ----------------
// OUTM: 0 = fp32 out (+opt residual), 2 = bf16 silu(gate)*up (interleaved W)
// NORMA: A fp32 [2048][216] rmsnorm'd on the fly; else A bf16 [2048][Kp].
template<int OUTM, bool NORMA>
__global__ __launch_bounds__(256, 2) void k_gemm_f(
    const void* __restrict__ Av, const unsigned short* __restrict__ W,
    const float* __restrict__ res, void* __restrict__ outv,
    const float* __restrict__ lnw, int N, int Kp)
{
    __shared__ __align__(16) unsigned short lds[2][2][4096];
    __shared__ float rsl[128];
    __shared__ float lnl[224];
    const int tid = threadIdx.x;
    const int m0 = blockIdx.x * 128;
    const int n0 = blockIdx.y * 128;
    const int wid = tid >> 6, lane = tid & 63;
    const int wr = wid >> 1, wc = wid & 1;
    const int nsteps = Kp >> 5;

    if constexpr (NORMA) {
        const float* Af = (const float*)Av;
        if (tid < 224) lnl[tid] = (tid < 216) ? lnw[tid] : 0.f;
        int row = tid >> 1, half = tid & 1;
        const float* xr = Af + (size_t)(m0 + row) * 216 + half * 108;
        float ss = 0.f;
        #pragma unroll
        for (int q = 0; q < 27; ++q) {
            float4 v = *(const float4*)(xr + q * 4);
            ss += v.x * v.x + v.y * v.y + v.z * v.z + v.w * v.w;
        }
        ss += __shfl_xor(ss, 1, 64);
        if (half == 0) rsl[row] = rsqrtf(ss / 216.f + EPSf);
        __syncthreads();
    }

    const int i0 = tid, i1 = tid + 256;
    const int rA0 = i0 >> 2, cA0 = i0 & 3;
    const int rA1 = i1 >> 2, cA1 = i1 & 3;
    const int lo0 = (rA0 >> 4) * 512 + (((cA0 << 4) | (rA0 & 15)) << 3);
    const int lo1 = (rA1 >> 4) * 512 + (((cA1 << 4) | (rA1 & 15)) << 3);

    auto loadA = [&](int row, int base) -> ushort8 {
        ushort8 o;
        if constexpr (NORMA) {
            if (base < 216) {
                const float* p = (const float*)Av + (size_t)(m0 + row) * 216 + base;
                float r = rsl[row];
                float4 v0 = *(const float4*)p;
                float4 v1 = *(const float4*)(p + 4);
                o[0] = f2bf(v0.x * r * lnl[base + 0]);
                o[1] = f2bf(v0.y * r * lnl[base + 1]);
                o[2] = f2bf(v0.z * r * lnl[base + 2]);
                o[3] = f2bf(v0.w * r * lnl[base + 3]);
                o[4] = f2bf(v1.x * r * lnl[base + 4]);
                o[5] = f2bf(v1.y * r * lnl[base + 5]);
                o[6] = f2bf(v1.z * r * lnl[base + 6]);
                o[7] = f2bf(v1.w * r * lnl[base + 7]);
            } else {
                #pragma unroll
                for (int e = 0; e < 8; ++e) o[e] = 0;
            }
        } else {
            o = *(const ushort8*)((const unsigned short*)Av + (size_t)(m0 + row) * Kp + base);
        }
        return o;
    };

    ushort8 ra0, ra1, rb0, rb1;
    ra0 = loadA(rA0, cA0 * 8);
    ra1 = loadA(rA1, cA1 * 8);
    rb0 = *(const ushort8*)(W + (size_t)(n0 + rA0) * Kp + cA0 * 8);
    rb1 = *(const ushort8*)(W + (size_t)(n0 + rA1) * Kp + cA1 * 8);
    *(ushort8*)&lds[0][0][lo0] = ra0;
    *(ushort8*)&lds[0][0][lo1] = ra1;
    *(ushort8*)&lds[0][1][lo0] = rb0;
    *(ushort8*)&lds[0][1][lo1] = rb1;
    __syncthreads();

    f32x4 acc[4][4] = {};

    int cur = 0;
    for (int step = 0; step < nsteps; ++step) {
        const bool more = (step + 1) < nsteps;
        if (more) {
            const int k0 = (step + 1) << 5;
            ra0 = loadA(rA0, k0 + cA0 * 8);
            ra1 = loadA(rA1, k0 + cA1 * 8);
            rb0 = *(const ushort8*)(W + (size_t)(n0 + rA0) * Kp + k0 + cA0 * 8);
            rb1 = *(const ushort8*)(W + (size_t)(n0 + rA1) * Kp + k0 + cA1 * 8);
        }
        short8 af[4], bf[4];
        #pragma unroll
        for (int f = 0; f < 4; ++f) {
            af[f] = *(const short8*)&lds[cur][0][(wr * 4 + f) * 512 + lane * 8];
            bf[f] = *(const short8*)&lds[cur][1][(wc * 4 + f) * 512 + lane * 8];
        }
        #pragma unroll
        for (int fm = 0; fm < 4; ++fm)
            #pragma unroll
            for (int fn = 0; fn < 4; ++fn)
                acc[fm][fn] = __builtin_amdgcn_mfma_f32_16x16x32_bf16(af[fm], bf[fn], acc[fm][fn], 0, 0, 0);
        if (more) {
            const int nxt = cur ^ 1;
            *(ushort8*)&lds[nxt][0][lo0] = ra0;
            *(ushort8*)&lds[nxt][0][lo1] = ra1;
            *(ushort8*)&lds[nxt][1][lo0] = rb0;
            *(ushort8*)&lds[nxt][1][lo1] = rb1;
            __syncthreads();
            cur = nxt;
        }
    }

    const int lc16 = lane & 15;
    #pragma unroll
    for (int fm = 0; fm < 4; ++fm) {
        const int mrow = m0 + wr * 64 + fm * 16 + (lane >> 4) * 4;
        #pragma unroll
        for (int fn = 0; fn < 4; ++fn) {
            const int ncol = n0 + wc * 64 + fn * 16 + lc16;
            #pragma unroll
            for (int i = 0; i < 4; ++i) {
                float v = acc[fm][fn][i];
                if constexpr (OUTM == 2) {
                    float p = __shfl_xor(v, 1, 64);
                    if ((lc16 & 1) == 0 && ncol < N) {
                        float y = v / (1.f + __expf(-v)) * p;
                        ((unsigned short*)outv)[(size_t)(mrow + i) * (N >> 1) + (ncol >> 1)] = f2bf(y);
                    }
                } else {
                    if (ncol < N) {
                        const size_t oi = (size_t)(mrow + i) * N + ncol;
                        if (res) v += res[oi];
                        ((float*)outv)[oi] = v;
                    }
                }
            }
        }
    }
}

// ---------------- qkv GEMM: norm-fused A, epilogue rope -> Qb/Kb, transpose -> Vt ---
__global__ __launch_bounds__(256, 2) void k_qkv(
    const float* __restrict__ Av, const unsigned short* __restrict__ W,
    const float* __restrict__ lnw,
    const float* __restrict__ cost, const float* __restrict__ sint,
    unsigned short* __restrict__ Qb, unsigned short* __restrict__ Kb,
    unsigned short* __restrict__ Vt)
{
    __shared__ __align__(16) unsigned short lds[2][2][4096];
    __shared__ float rsl[128];
    __shared__ float lnl[224];
    const int tid = threadIdx.x;
    const int m0 = blockIdx.x * 128;
    const int n0 = blockIdx.y * 128;
    const int wid = tid >> 6, lane = tid & 63;
    const int wr = wid >> 1, wc = wid & 1;
    const int nsteps = KP >> 5;

    // rmsnorm prologue
    {
        if (tid < 224) lnl[tid] = (tid < 216) ? lnw[tid] : 0.f;
        int row = tid >> 1, half = tid & 1;
        const float* xr = Av + (size_t)(m0 + row) * 216 + half * 108;
        float ss = 0.f;
        #pragma unroll
        for (int q = 0; q < 27; ++q) {
            float4 v = *(const float4*)(xr + q * 4);
            ss += v.x * v.x + v.y * v.y + v.z * v.z + v.w * v.w;
        }
        ss += __shfl_xor(ss, 1, 64);
        if (half == 0) rsl[row] = rsqrtf(ss / 216.f + EPSf);
        __syncthreads();
    }

    const int i0 = tid, i1 = tid + 256;
    const int rA0 = i0 >> 2, cA0 = i0 & 3;
    const int rA1 = i1 >> 2, cA1 = i1 & 3;
    const int lo0 = (rA0 >> 4) * 512 + (((cA0 << 4) | (rA0 & 15)) << 3);
    const int lo1 = (rA1 >> 4) * 512 + (((cA1 << 4) | (rA1 & 15)) << 3);

    auto loadA = [&](int row, int base) -> ushort8 {
        ushort8 o;
        if (base < 216) {
            const float* p = Av + (size_t)(m0 + row) * 216 + base;
            float r = rsl[row];
            float4 v0 = *(const float4*)p;
            float4 v1 = *(const float4*)(p + 4);
            o[0] = f2bf(v0.x * r * lnl[base + 0]);
            o[1] = f2bf(v0.y * r * lnl[base + 1]);
            o[2] = f2bf(v0.z * r * lnl[base + 2]);
            o[3] = f2bf(v0.w * r * lnl[base + 3]);
            o[4] = f2bf(v1.x * r * lnl[base + 4]);
            o[5] = f2bf(v1.y * r * lnl[base + 5]);
            o[6] = f2bf(v1.z * r * lnl[base + 6]);
            o[7] = f2bf(v1.w * r * lnl[base + 7]);
        } else {
            #pragma unroll
            for (int e = 0; e < 8; ++e) o[e] = 0;
        }
        return o;
    };

    ushort8 ra0, ra1, rb0, rb1;
    ra0 = loadA(rA0, cA0 * 8);
    ra1 = loadA(rA1, cA1 * 8);
    rb0 = *(const ushort8*)(W + (size_t)(n0 + rA0) * KP + cA0 * 8);
    rb1 = *(const ushort8*)(W + (size_t)(n0 + rA1) * KP + cA1 * 8);
    *(ushort8*)&lds[0][0][lo0] = ra0;
    *(ushort8*)&lds[0][0][lo1] = ra1;
    *(ushort8*)&lds[0][1][lo0] = rb0;
    *(ushort8*)&lds[0][1][lo1] = rb1;
    __syncthreads();

    f32x4 acc[4][4] = {};
    int cur = 0;
    for (int step = 0; step < nsteps; ++step) {
        const bool more = (step + 1) < nsteps;
        if (more) {
            const int k0 = (step + 1) << 5;
            ra0 = loadA(rA0, k0 + cA0 * 8);
            ra1 = loadA(rA1, k0 + cA1 * 8);
            rb0 = *(const ushort8*)(W + (size_t)(n0 + rA0) * KP + k0 + cA0 * 8);
            rb1 = *(const ushort8*)(W + (size_t)(n0 + rA1) * KP + k0 + cA1 * 8);
        }
        short8 af[4], bf[4];
        #pragma unroll
        for (int f = 0; f < 4; ++f) {
            af[f] = *(const short8*)&lds[cur][0][(wr * 4 + f) * 512 + lane * 8];
            bf[f] = *(const short8*)&lds[cur][1][(wc * 4 + f) * 512 + lane * 8];
        }
        #pragma unroll
        for (int fm = 0; fm < 4; ++fm)
            #pragma unroll
            for (int fn = 0; fn < 4; ++fn)
                acc[fm][fn] = __builtin_amdgcn_mfma_f32_16x16x32_bf16(af[fm], bf[fn], acc[fm][fn], 0, 0, 0);
        if (more) {
            const int nxt = cur ^ 1;
            *(ushort8*)&lds[nxt][0][lo0] = ra0;
            *(ushort8*)&lds[nxt][0][lo1] = ra1;
            *(ushort8*)&lds[nxt][1][lo0] = rb0;
            *(ushort8*)&lds[nxt][1][lo1] = rb1;
            __syncthreads();
            cur = nxt;
        }
    }

    // epilogue: rope q/k (paired cols, partner via shfl_xor 1), transpose v
    const int lc16 = lane & 15;
    #pragma unroll
    for (int fm = 0; fm < 4; ++fm) {
        const int mrow = m0 + wr * 64 + fm * 16 + (lane >> 4) * 4;
        const int b = mrow >> 10;
        const int st0 = mrow & 1023;
        #pragma unroll
        for (int fn = 0; fn < 4; ++fn) {
            const int ncol = n0 + wc * 64 + fn * 16 + lc16;
            float v0 = acc[fm][fn][0], v1 = acc[fm][fn][1];
            float v2 = acc[fm][fn][2], v3 = acc[fm][fn][3];
            float p0 = __shfl_xor(v0, 1, 64);
            float p1 = __shfl_xor(v1, 1, 64);
            float p2 = __shfl_xor(v2, 1, 64);
            float p3 = __shfl_xor(v3, 1, 64);
            if (ncol < 432) {
                int which = ncol >= 216;
                int cih = ncol - which * 216;
                int head = cih / 54, dd = cih % 54;
                int j = dd >> 1;
                bool odd = dd & 1;
                unsigned short* dst = (which ? Kb : Qb) +
                    ((size_t)(b * NHh + head) * Ss + st0) * HDP + dd;
                float vv[4] = {v0, v1, v2, v3};
                float pp[4] = {p0, p1, p2, p3};
                #pragma unroll
                for (int i = 0; i < 4; ++i) {
                    float c = cost[(st0 + i) * 27 + j];
                    float sn = sint[(st0 + i) * 27 + j];
                    float o = odd ? (vv[i] * c + pp[i] * sn) : (vv[i] * c - pp[i] * sn);
                    dst[(size_t)i * HDP] = f2bf(o);
                }
            } else if (ncol < 648) {
                int d = ncol - 432;
                int head = d / 54, dd = d % 54;
                ushort4 pk;
                pk.x = f2bf(v0); pk.y = f2bf(v1); pk.z = f2bf(v2); pk.w = f2bf(v3);
                *(ushort4*)(Vt + (size_t)(b * NHh + head) * VTSZ + (size_t)dd * Ss + st0) = pk;
            }
        }
    }
}

// ---------------- small residual GEMM: 64x64 tile, x += A*W^T ----------------
__global__ __launch_bounds__(256) void k_gemm_s(
    const unsigned short* __restrict__ A, const unsigned short* __restrict__ W,
    float* __restrict__ xio, int N, int Kp)
{
    __shared__ __align__(16) unsigned short lA[2][2048];
    __shared__ __align__(16) unsigned short lB[2][2048];
    const int tid = threadIdx.x;
    const int m0 = blockIdx.x * 64, n0 = blockIdx.y * 64;
    const int wid = tid >> 6, lane = tid & 63;
    const int wr = wid >> 1, wc = wid & 1;
    const int nsteps = Kp >> 5;
    const int r = tid >> 2, kc = tid & 3;
    const int lo = (r >> 4) * 512 + (((kc << 4) | (r & 15)) << 3);

    ushort8 ra = *(const ushort8*)(A + (size_t)(m0 + r) * Kp + kc * 8);
    ushort8 rb = *(const ushort8*)(W + (size_t)(n0 + r) * Kp + kc * 8);
    *(ushort8*)&lA[0][lo] = ra;
    *(ushort8*)&lB[0][lo] = rb;
    __syncthreads();

    f32x4 acc[2][2] = {};
    int cur = 0;
    for (int step = 0; step < nsteps; ++step) {
        const bool more = (step + 1) < nsteps;
        if (more) {
            const int k0 = (step + 1) << 5;
            ra = *(const ushort8*)(A + (size_t)(m0 + r) * Kp + k0 + kc * 8);
            rb = *(const ushort8*)(W + (size_t)(n0 + r) * Kp + k0 + kc * 8);
        }
        short8 af[2], bf[2];
        #pragma unroll
        for (int f = 0; f < 2; ++f) {
            af[f] = *(const short8*)&lA[cur][(wr * 2 + f) * 512 + lane * 8];
            bf[f] = *(const short8*)&lB[cur][(wc * 2 + f) * 512 + lane * 8];
        }
        #pragma unroll
        for (int fm = 0; fm < 2; ++fm)
            #pragma unroll
            for (int fn = 0; fn < 2; ++fn)
                acc[fm][fn] = __builtin_amdgcn_mfma_f32_16x16x32_bf16(af[fm], bf[fn], acc[fm][fn], 0, 0, 0);
        if (more) {
            const int nxt = cur ^ 1;
            *(ushort8*)&lA[nxt][lo] = ra;
            *(ushort8*)&lB[nxt][lo] = rb;
            __syncthreads();
            cur = nxt;
        }
    }

    #pragma unroll
    for (int fm = 0; fm < 2; ++fm) {
        const int mrow = m0 + wr * 32 + fm * 16 + (lane >> 4) * 4;
        #pragma unroll
        for (int fn = 0; fn < 2; ++fn) {
            const int ncol = n0 + wc * 32 + fn * 16 + (lane & 15);
            if (ncol < N) {
                #pragma unroll
                for (int i = 0; i < 4; ++i) {
                    const size_t oi = (size_t)(mrow + i) * N + ncol;
                    xio[oi] += acc[fm][fn][i];
                }
            }
        }
    }
}

// ---------------- MFMA flash attention (reads prepped Qb/Kb/Vt) ----------------
__global__ __launch_bounds__(128) void k_attn_fa(
    const unsigned short* __restrict__ Qb, const unsigned short* __restrict__ Kb,
    const unsigned short* __restrict__ Vt, unsigned short* __restrict__ aout)
{
    __shared__ __align__(16) unsigned short Kl[4096];
    __shared__ __align__(16) unsigned short Vl[4096];
    __shared__ __align__(16) unsigned short Pl[2048];
    const int tid = threadIdx.x;
    const int qb = blockIdx.x, h = blockIdx.y, b = blockIdx.z;
    const int bh = b * NHh + h;
    const int q0 = qb * 32;
    const int w = tid >> 6, lane = tid & 63;
    const int q0w = q0 + w * 16;
    const int lc = lane & 15, lg = lane >> 4;

    const unsigned short* Qp = Qb + (size_t)bh * VTSZ;
    const unsigned short* Kpp = Kb + (size_t)bh * VTSZ;
    const unsigned short* Vp = Vt + (size_t)bh * VTSZ;

    short8 qa[2];
    #pragma unroll
    for (int half = 0; half < 2; ++half)
        qa[half] = *(const short8*)(Qp + (size_t)(q0w + lc) * HDP + lg * 8 + half * 32);

    f32x4 o4[4] = {};
    float mreg[4] = {-3e38f, -3e38f, -3e38f, -3e38f};
    float lreg[4] = {0.f, 0.f, 0.f, 0.f};

    const int nt = (q0 + 31) / 64 + 1;
    for (int t = 0; t < nt; ++t) {
        const int kv0 = t * 64;
        if (t) __syncthreads();
        for (int c = tid; c < 1024; c += 128) {
            if (c < 512) {
                int sub = c >> 6;
                int dhalf = sub >> 2, kgrp = sub & 3;
                int dchunk = (c >> 4) & 3, krow = c & 15;
                *(ushort8*)&Kl[sub * 512 + (c & 63) * 8] =
                    *(const ushort8*)(Kpp + (size_t)(kv0 + kgrp * 16 + krow) * HDP + dhalf * 32 + dchunk * 8);
            } else {
                int c2 = c - 512;
                int sub2 = c2 >> 6;
                int khalf = sub2 >> 2, dgrp = sub2 & 3;
                int kchunk = (c2 >> 4) & 3, drow = c2 & 15;
                *(ushort8*)&Vl[sub2 * 512 + (c2 & 63) * 8] =
                    *(const ushort8*)(Vp + (size_t)(dgrp * 16 + drow) * Ss + kv0 + khalf * 32 + kchunk * 8);
            }
        }
        __syncthreads();

        // QK^T: S[16q][64k]
        f32x4 s4[4] = {};
        #pragma unroll
        for (int half = 0; half < 2; ++half) {
            #pragma unroll
            for (int fn = 0; fn < 4; ++fn) {
                short8 kf = *(const short8*)&Kl[(half * 4 + fn) * 512 + lane * 8];
                s4[fn] = __builtin_amdgcn_mfma_f32_16x16x32_bf16(qa[half], kf, s4[fn], 0, 0, 0);
            }
        }
        // causal mask: needed whenever tile's max k exceeds wave's LOWEST q-row
        if (kv0 + 63 > q0w) {
            #pragma unroll
            for (int fn = 0; fn < 4; ++fn) {
                int kg = kv0 + fn * 16 + lc;
                #pragma unroll
                for (int r = 0; r < 4; ++r) {
                    int qg = q0w + lg * 4 + r;
                    if (kg > qg) s4[fn][r] = -3e38f;
                }
            }
        }
        // online softmax (each q-row lives in a 16-lane group)
        #pragma unroll
        for (int r = 0; r < 4; ++r) {
            float rm = fmaxf(fmaxf(s4[0][r], s4[1][r]), fmaxf(s4[2][r], s4[3][r]));
            #pragma unroll
            for (int msk = 1; msk < 16; msk <<= 1)
                rm = fmaxf(rm, __shfl_xor(rm, msk, 64));
            float mn = fmaxf(mreg[r], rm);
            float esc = __expf(mreg[r] - mn);
            mreg[r] = mn;
            float p0 = __expf(s4[0][r] - mn);
            float p1 = __expf(s4[1][r] - mn);
            float p2 = __expf(s4[2][r] - mn);
            float p3 = __expf(s4[3][r] - mn);
            float rs = p0 + p1 + p2 + p3;
            #pragma unroll
            for (int msk = 1; msk < 16; msk <<= 1)
                rs += __shfl_xor(rs, msk, 64);
            lreg[r] = lreg[r] * esc + rs;
            #pragma unroll
            for (int db = 0; db < 4; ++db) o4[db][r] *= esc;
            int q = lg * 4 + r;
            int kc = lc >> 3, ko = lc & 7;
            Pl[w * 1024 + ((0 * 2 + kc) * 16 + q) * 8 + ko] = f2bf(p0);
            Pl[w * 1024 + ((1 * 2 + kc) * 16 + q) * 8 + ko] = f2bf(p1);
            Pl[w * 1024 + ((2 * 2 + kc) * 16 + q) * 8 + ko] = f2bf(p2);
            Pl[w * 1024 + ((3 * 2 + kc) * 16 + q) * 8 + ko] = f2bf(p3);
        }
        // PV
        short8 pa0 = *(const short8*)&Pl[w * 1024 + ((0 + lg) * 16 + lc) * 8];
        short8 pa1 = *(const short8*)&Pl[w * 1024 + ((4 + lg) * 16 + lc) * 8];
        #pragma unroll
        for (int db = 0; db < 4; ++db) {
            short8 vf0 = *(const short8*)&Vl[(0 + db) * 512 + lane * 8];
            o4[db] = __builtin_amdgcn_mfma_f32_16x16x32_bf16(pa0, vf0, o4[db], 0, 0, 0);
            short8 vf1 = *(const short8*)&Vl[(4 + db) * 512 + lane * 8];
            o4[db] = __builtin_amdgcn_mfma_f32_16x16x32_bf16(pa1, vf1, o4[db], 0, 0, 0);
        }
    }

    #pragma unroll
    for (int r = 0; r < 4; ++r) {
        float inv = 1.f / lreg[r];
        int row = b * Ss + q0w + lg * 4 + r;
        #pragma unroll
        for (int db = 0; db < 4; ++db) {
            int col = db * 16 + lc;
            if (col < HDd)
                aout[(size_t)row * KP + h * HDd + col] = f2bf(o4[db][r] * inv);
        }
    }
}

// ================= legacy fp32 fallback kernels =================
__global__ void k_rmsnorm(const float* __restrict__ x, const float* __restrict__ w,
                          float* __restrict__ h) {
    int t = blockIdx.x;
    const float* xr = x + (size_t)t * Dm;
    float ss = 0.f;
    for (int d = threadIdx.x; d < Dm; d += 64) { float v = xr[d]; ss += v * v; }
    for (int o = 32; o; o >>= 1) ss += __shfl_down(ss, o, 64);
    float r = __shfl(ss, 0, 64);
    r = rsqrtf(r / (float)Dm + EPSf);
    for (int d = threadIdx.x; d < Dm; d += 64)
        h[(size_t)t * Dm + d] = xr[d] * r * w[d];
}

#define TS 16
__global__ void k_gemm(const float* __restrict__ A, const float* __restrict__ W,
                       const float* __restrict__ res, float* __restrict__ out,
                       int M, int N, int K) {
    __shared__ float As[TS][TS + 1];
    __shared__ float Wsm[TS][TS + 1];
    const int tx = threadIdx.x, ty = threadIdx.y;
    const int m = blockIdx.y * TS + ty;
    const int n = blockIdx.x * TS + tx;
    float acc = 0.f;
    for (int k0 = 0; k0 < K; k0 += TS) {
        int ka = k0 + tx;
        As[ty][tx] = (m < M && ka < K) ? A[(size_t)m * K + ka] : 0.f;
        int nw = blockIdx.x * TS + ty;
        Wsm[ty][tx] = (nw < N && ka < K) ? W[(size_t)nw * K + ka] : 0.f;
        __syncthreads();
        #pragma unroll
        for (int kk = 0; kk < TS; ++kk) acc += As[ty][kk] * Wsm[tx][kk];
        __syncthreads();
    }
    if (m < M && n < N) {
        float r = res ? res[(size_t)m * N + n] : 0.f;
        out[(size_t)m * N + n] = r + acc;
    }
}

__global__ void k_gateup(const float* __restrict__ A, const float* __restrict__ Wg,
                         const float* __restrict__ Wu, float* __restrict__ act,
                         int M, int N, int K) {
    __shared__ float As[TS][TS + 1];
    __shared__ float Gs[TS][TS + 1];
    __shared__ float Us[TS][TS + 1];
    const int tx = threadIdx.x, ty = threadIdx.y;
    const int m = blockIdx.y * TS + ty;
    const int n = blockIdx.x * TS + tx;
    float ag = 0.f, au = 0.f;
    for (int k0 = 0; k0 < K; k0 += TS) {
        int ka = k0 + tx;
        As[ty][tx] = (m < M && ka < K) ? A[(size_t)m * K + ka] : 0.f;
        int nw = blockIdx.x * TS + ty;
        Gs[ty][tx] = (nw < N && ka < K) ? Wg[(size_t)nw * K + ka] : 0.f;
        Us[ty][tx] = (nw < N && ka < K) ? Wu[(size_t)nw * K + ka] : 0.f;
        __syncthreads();
        #pragma unroll
        for (int kk = 0; kk < TS; ++kk) {
            ag += As[ty][kk] * Gs[tx][kk];
            au += As[ty][kk] * Us[tx][kk];
        }
        __syncthreads();
    }
    if (m < M && n < N) {
        float sg = ag / (1.f + expf(-ag));
        act[(size_t)m * N + n] = sg * au;
    }
}

__global__ void k_rope(float* __restrict__ qkv, const float* __restrict__ cosb,
                       const float* __restrict__ sinb) {
    const int t = blockIdx.x;
    const int s = t % Ss;
    float* base = qkv + (size_t)t * QKVW;
    const int HALF = HDd / 2;
    int i = threadIdx.x;
    if (i < 2 * NHh * HALF) {
        int which = i / (NHh * HALF);
        int rem = i % (NHh * HALF);
        int hh = rem / HALF;
        int d = rem % HALF;
        float* ptr = base + which * Dm + hh * HDd;
        float x1 = ptr[d], x2 = ptr[d + HALF];
        float c1 = cosb[s * HDd + d], s1 = sinb[s * HDd + d];
        float c2 = cosb[s * HDd + d + HALF], s2 = sinb[s * HDd + d + HALF];
        ptr[d]        = x1 * c1 - x2 * s1;
        ptr[d + HALF] = x2 * c2 + x1 * s2;
    }
}

__global__ void k_attn(const float* __restrict__ qkv, float* __restrict__ aout) {
    const int q = blockIdx.x, h = blockIdx.y, b = blockIdx.z;
    const int tid = threadIdx.x;
    __shared__ float p[Ss];
    __shared__ float qv[HDd];
    __shared__ float rmax[4], rsum[4];
    const size_t base = (size_t)b * Ss * QKVW;
    const float* qrow = qkv + base + (size_t)q * QKVW + h * HDd;
    if (tid < HDd) qv[tid] = qrow[tid];
    __syncthreads();
    const int nk = q + 1;
    const float scale = 0.13608276348795434f;
    float lmax = -3.0e38f;
    for (int k = tid; k < nk; k += 256) {
        const float* krow = qkv + base + (size_t)k * QKVW + Dm + h * HDd;
        float acc = 0.f;
        #pragma unroll
        for (int d = 0; d < HDd; ++d) acc += qv[d] * krow[d];
        acc *= scale;
        p[k] = acc;
        lmax = fmaxf(lmax, acc);
    }
    for (int o = 32; o; o >>= 1) lmax = fmaxf(lmax, __shfl_down(lmax, o, 64));
    if ((tid & 63) == 0) rmax[tid >> 6] = lmax;
    __syncthreads();
    const float m = fmaxf(fmaxf(rmax[0], rmax[1]), fmaxf(rmax[2], rmax[3]));
    float lsum = 0.f;
    for (int k = tid; k < nk; k += 256) {
        float e = expf(p[k] - m);
        p[k] = e;
        lsum += e;
    }
    for (int o = 32; o; o >>= 1) lsum += __shfl_down(lsum, o, 64);
    if ((tid & 63) == 0) rsum[tid >> 6] = lsum;
    __syncthreads();
    const float inv = 1.f / (rsum[0] + rsum[1] + rsum[2] + rsum[3]);
    for (int d = tid; d < HDd; d += 256) {
        const float* vcol = qkv + base + 2 * Dm + h * HDd + d;
        float acc = 0.f;
        for (int k = 0; k < nk; ++k) acc += p[k] * vcol[(size_t)k * QKVW];
        aout[(size_t)(b * Ss + q) * Dm + h * HDd + d] = acc * inv;
    }
}

// =====================================================================
extern "C" void kernel_launch(void* const* d_in, const int* in_sizes, int n_in,
                              void* d_out, int out_size, void* d_ws, size_t ws_size,
                              hipStream_t stream) {
    const int*   ids    = (const int*)d_in[0];
    const float* emb    = (const float*)d_in[1];
    const float* ln1_w  = (const float*)d_in[2];
    const float* qkv_w  = (const float*)d_in[3];
    const float* o_w    = (const float*)d_in[4];
    const float* ln2_w  = (const float*)d_in[5];
    const float* gate_w = (const float*)d_in[6];
    const float* up_w   = (const float*)d_in[7];
    const float* down_w = (const float*)d_in[8];
    const float* norm_w = (const float*)d_in[9];
    const float* lm_w   = (const float*)d_in[10];
    float* out = (float*)d_out;

    char* base = (char*)d_ws;
    size_t off = 0;
    auto carve = [&](size_t bytes) -> char* {
        char* p = base + off;
        off += (bytes + 255) & ~(size_t)255;
        return p;
    };

    // fp32 buffers
    float* x     = (float*)carve((size_t)Tt * Dm * 4);
    float* cos27 = (float*)carve((size_t)Ss * 27 * 4);
    float* sin27 = (float*)carve((size_t)Ss * 27 * 4);
    // bf16 buffers (Qb..aout contiguous, zeroed once for pads)
    unsigned short* Qb   = (unsigned short*)carve((size_t)Bb * NHh * VTSZ * 2);
    unsigned short* Kb   = (unsigned short*)carve((size_t)Bb * NHh * VTSZ * 2);
    unsigned short* Vt   = (unsigned short*)carve((size_t)Bb * NHh * VTSZ * 2);
    unsigned short* aout = (unsigned short*)carve((size_t)Tt * KP * 2);
    char* zend = base + off;
    unsigned short* act  = (unsigned short*)carve((size_t)Tt * FFf * 2);
    unsigned short* qkvw = (unsigned short*)carve((size_t)NLAY * 768 * KP * 2);
    unsigned short* ow   = (unsigned short*)carve((size_t)NLAY * 256 * KP * 2);
    unsigned short* guw  = (unsigned short*)carve((size_t)NLAY * 1792 * KP * 2);
    unsigned short* dww  = (unsigned short*)carve((size_t)NLAY * 256 * 864 * 2);
    unsigned short* lmw  = (unsigned short*)carve((size_t)Vv * KP * 2);
    size_t need = off;

    if (ws_size >= need) {
        // -------- fused bf16 MFMA path --------
        k_embed<<<Tt, 256, 0, stream>>>(ids, emb, x);
        k_rope_tables27<<<Ss, 32, 0, stream>>>(cos27, sin27);
        size_t zwords = (size_t)(zend - (char*)Qb) / 4;
        k_zero<<<2048, 256, 0, stream>>>((unsigned int*)Qb, zwords);

        k_convqkv<<<512, 256, 0, stream>>>(qkv_w, qkvw);
        k_convw<<<256, 256, 0, stream>>>(o_w,   ow,   NLAY, Dm,   Dm, 256, KP, KP, 256L * KP, 0);
        k_convw<<<512, 256, 0, stream>>>(gate_w, guw, NLAY, FFf,  Dm, 896, KP, 2 * KP, 1792L * KP, 0);
        k_convw<<<512, 256, 0, stream>>>(up_w,   guw, NLAY, FFf,  Dm, 896, KP, 2 * KP, 1792L * KP, KP);
        k_convw<<<512, 256, 0, stream>>>(down_w, dww, NLAY, Dm,  FFf, 256, 864, 864, 256L * 864, 0);
        k_convw<<<1024, 256, 0, stream>>>(lm_w,  lmw, 1,    Vv,   Dm, Vv,  KP, KP, (long)Vv * KP, 0);

        for (int l = 0; l < NLAY; ++l) {
            k_qkv<<<dim3(16, 6), 256, 0, stream>>>(
                x, qkvw + (size_t)l * 768 * KP, ln1_w + (size_t)l * Dm,
                cos27, sin27, Qb, Kb, Vt);
            k_attn_fa<<<dim3(Ss / 32, NHh, Bb), 128, 0, stream>>>(Qb, Kb, Vt, aout);
            k_gemm_s<<<dim3(32, 4), 256, 0, stream>>>(
                aout, ow + (size_t)l * 256 * KP, x, Dm, KP);
            k_gemm_f<2, true><<<dim3(16, 14), 256, 0, stream>>>(
                x, guw + (size_t)l * 1792 * KP, nullptr, act,
                ln2_w + (size_t)l * Dm, 2 * FFf, KP);
            k_gemm_s<<<dim3(32, 4), 256, 0, stream>>>(
                act, dww + (size_t)l * 256 * 864, x, Dm, 864);
        }
        k_gemm_f<0, true><<<dim3(16, 250), 256, 0, stream>>>(
            x, lmw, nullptr, out, norm_w, Vv, KP);
    } else {
        // -------- legacy fp32 fallback --------
        float* ws = (float*)d_ws;
        size_t o2 = 0;
        float* x2    = ws + o2; o2 += (size_t)Tt * Dm;
        float* h2    = ws + o2; o2 += (size_t)Tt * Dm;
        float* qkv2  = ws + o2; o2 += (size_t)Tt * QKVW;
        float* aout2 = ws + o2; o2 += (size_t)Tt * Dm;
        float* act2  = ws + o2; o2 += (size_t)Tt * FFf;
        float* cosb2 = ws + o2; o2 += (size_t)Ss * HDd;
        float* sinb2 = ws + o2; o2 += (size_t)Ss * HDd;

        k_embed<<<Tt, 256, 0, stream>>>(ids, emb, x2);
        k_rope_tables<<<Ss, 64, 0, stream>>>(cosb2, sinb2);
        dim3 blk(TS, TS);
        for (int l = 0; l < NLAY; ++l) {
            k_rmsnorm<<<Tt, 64, 0, stream>>>(x2, ln1_w + (size_t)l * Dm, h2);
            k_gemm<<<dim3((QKVW + TS - 1) / TS, (Tt + TS - 1) / TS), blk, 0, stream>>>(
                h2, qkv_w + (size_t)l * QKVW * Dm, nullptr, qkv2, Tt, QKVW, Dm);
            k_rope<<<Tt, 256, 0, stream>>>(qkv2, cosb2, sinb2);
            k_attn<<<dim3(Ss, NHh, Bb), 256, 0, stream>>>(qkv2, aout2);
            k_gemm<<<dim3((Dm + TS - 1) / TS, (Tt + TS - 1) / TS), blk, 0, stream>>>(
                aout2, o_w + (size_t)l * Dm * Dm, x2, x2, Tt, Dm, Dm);
            k_rmsnorm<<<Tt, 64, 0, stream>>>(x2, ln2_w + (size_t)l * Dm, h2);
            k_gateup<<<dim3((FFf + TS - 1) / TS, (Tt + TS - 1) / TS), blk, 0, stream>>>(
                h2, gate_w + (size_t)l * FFf * Dm, up_w + (size_t)l * FFf * Dm, act2, Tt, FFf, Dm);
            k_gemm<<<dim3((Dm + TS - 1) / TS, (Tt + TS - 1) / TS), blk, 0, stream>>>(
                act2, down_w + (size_t)l * Dm * FFf, x2, x2, Tt, Dm, FFf);
        }
        k_rmsnorm<<<Tt, 64, 0, stream>>>(x2, norm_w, h2);
        k_gemm<<<dim3((Vv + TS - 1) / TS, (Tt + TS - 1) / TS), blk, 0, stream>>>(
            h2, lm_w, nullptr, out, Tt, Vv, Dm);
    }
}